// Round 8
// baseline (4403.798 us; speedup 1.0000x reference)
//
#include <hip/hip_runtime.h>
#include <hip/hip_bf16.h>
#include <math.h>

// Problem constants (B=8, N=1024, D=256, L=4, M=1024, H=8, dh=32, K=64 clusters)
#define BN 8192           // B*N rows
#define DMODEL 256
#define FFN 1024
#define NCLUST 64

// ---------------- LayerNorm: one wave per row, float4 + shuffle reduce, no barriers ----------------
__global__ __launch_bounds__(256) void ln_wave(const float* __restrict__ x, const float* __restrict__ g,
                                               const float* __restrict__ b, float* __restrict__ y) {
    int t = threadIdx.x, w = t >> 6, l = t & 63;
    int row = blockIdx.x * 4 + w;
    const float* xr = x + (size_t)row * DMODEL;
    float4 v = *reinterpret_cast<const float4*>(xr + l * 4);
    float s = v.x + v.y + v.z + v.w;
    for (int off = 1; off < 64; off <<= 1) s += __shfl_xor(s, off);
    float mean = s * (1.0f / 256.0f);
    float4 dv = make_float4(v.x - mean, v.y - mean, v.z - mean, v.w - mean);
    float vs = dv.x * dv.x + dv.y * dv.y + dv.z * dv.z + dv.w * dv.w;
    for (int off = 1; off < 64; off <<= 1) vs += __shfl_xor(vs, off);
    float rs = rsqrtf(vs * (1.0f / 256.0f) + 1e-5f);
    float4 gg = *reinterpret_cast<const float4*>(g + l * 4);
    float4 bb = *reinterpret_cast<const float4*>(b + l * 4);
    float4 out = make_float4(dv.x * rs * gg.x + bb.x, dv.y * rs * gg.y + bb.y,
                             dv.z * rs * gg.z + bb.z, dv.w * rs * gg.w + bb.w);
    *reinterpret_cast<float4*>(y + (size_t)row * DMODEL + l * 4) = out;
}

// ---------------- GEMM big: 128x64 tile, BK=16, 8x4 microtile ----------------
// Per-output k-chain identical to naive (k0 asc, kk asc) -> numerics preserved.
__global__ __launch_bounds__(256) void gemm_big(const float* __restrict__ A, const float* __restrict__ W,
                                                const float* __restrict__ bias, const float* __restrict__ resid,
                                                float* __restrict__ C, int M, int Nn, int K, int fuse_gelu) {
    __shared__ float As[16][128];
    __shared__ float Bs[16][64];
    int t = threadIdx.x, tx = t & 15, ty = t >> 4;
    int m0 = blockIdx.y * 128, n0 = blockIdx.x * 64;
    float acc[8][4] = {};
    for (int k0 = 0; k0 < K; k0 += 16) {
        {   // stage A transposed: As[kk][m]; 128 rows x 16 k, 8 floats/thread
            int mr = t >> 1, kq = (t & 1) * 8;
            const float* src = A + (size_t)(m0 + mr) * K + k0 + kq;
            float4 a4 = *reinterpret_cast<const float4*>(src);
            float4 a5 = *reinterpret_cast<const float4*>(src + 4);
            As[kq][mr] = a4.x; As[kq + 1][mr] = a4.y; As[kq + 2][mr] = a4.z; As[kq + 3][mr] = a4.w;
            As[kq + 4][mr] = a5.x; As[kq + 5][mr] = a5.y; As[kq + 6][mr] = a5.z; As[kq + 7][mr] = a5.w;
        }
        {   // stage B: Bs[kk][n]
            int kk = t >> 4, nq = (t & 15) * 4;
            *reinterpret_cast<float4*>(&Bs[kk][nq]) =
                *reinterpret_cast<const float4*>(W + (size_t)(k0 + kk) * Nn + n0 + nq);
        }
        __syncthreads();
#pragma unroll
        for (int kk = 0; kk < 16; kk++) {
            float4 a0 = *reinterpret_cast<float4*>(&As[kk][ty * 8]);
            float4 a1 = *reinterpret_cast<float4*>(&As[kk][ty * 8 + 4]);
            float4 b4 = *reinterpret_cast<float4*>(&Bs[kk][tx * 4]);
            float a[8] = {a0.x, a0.y, a0.z, a0.w, a1.x, a1.y, a1.z, a1.w};
            float bf[4] = {b4.x, b4.y, b4.z, b4.w};
#pragma unroll
            for (int i = 0; i < 8; i++)
#pragma unroll
                for (int j = 0; j < 4; j++) acc[i][j] += a[i] * bf[j];
        }
        __syncthreads();
    }
#pragma unroll
    for (int i = 0; i < 8; i++) {
#pragma unroll
        for (int j = 0; j < 4; j++) {
            int row = m0 + ty * 8 + i, col = n0 + tx * 4 + j;
            float v = acc[i][j];
            if (bias) v += bias[col];
            if (fuse_gelu) v = 0.5f * v * (1.0f + erff(v * 0.70710678118654752f));
            if (resid) v += resid[(size_t)row * Nn + col];
            C[(size_t)row * Nn + col] = v;
        }
    }
}

// ---------------- GEMM 64x64 (proven) for W2 ----------------
__global__ __launch_bounds__(256) void gemm64(const float* __restrict__ A, const float* __restrict__ W,
                                              const float* __restrict__ bias, const float* __restrict__ resid,
                                              float* __restrict__ C, int M, int Nn, int K, int fuse_gelu) {
    __shared__ float As[16][64];
    __shared__ float Bs[16][64];
    int t = threadIdx.x, tx = t & 15, ty = t >> 4;
    int m0 = blockIdx.y * 64, n0 = blockIdx.x * 64;
    float acc[4][4] = {};
    for (int k0 = 0; k0 < K; k0 += 16) {
        {
            int mr = t >> 2, kq = (t & 3) * 4;
            float4 a4 = *reinterpret_cast<const float4*>(A + (size_t)(m0 + mr) * K + k0 + kq);
            As[kq][mr] = a4.x; As[kq + 1][mr] = a4.y; As[kq + 2][mr] = a4.z; As[kq + 3][mr] = a4.w;
        }
        {
            int kk = t >> 4, nq = (t & 15) * 4;
            *reinterpret_cast<float4*>(&Bs[kk][nq]) =
                *reinterpret_cast<const float4*>(W + (size_t)(k0 + kk) * Nn + n0 + nq);
        }
        __syncthreads();
#pragma unroll
        for (int kk = 0; kk < 16; kk++) {
            float4 a4 = *reinterpret_cast<float4*>(&As[kk][ty * 4]);
            float4 b4 = *reinterpret_cast<float4*>(&Bs[kk][tx * 4]);
            float a[4] = {a4.x, a4.y, a4.z, a4.w};
            float bf[4] = {b4.x, b4.y, b4.z, b4.w};
#pragma unroll
            for (int i = 0; i < 4; i++)
#pragma unroll
                for (int j = 0; j < 4; j++) acc[i][j] += a[i] * bf[j];
        }
        __syncthreads();
    }
#pragma unroll
    for (int i = 0; i < 4; i++) {
#pragma unroll
        for (int j = 0; j < 4; j++) {
            int row = m0 + ty * 4 + i, col = n0 + tx * 4 + j;
            float v = acc[i][j];
            if (bias) v += bias[col];
            if (fuse_gelu) v = 0.5f * v * (1.0f + erff(v * 0.70710678118654752f));
            if (resid) v += resid[(size_t)row * Nn + col];
            C[(size_t)row * Nn + col] = v;
        }
    }
}

// ---------------- Attention v2c: two-pass, b128 LDS everywhere ----------------
// Same accumulation orders as the proven attn2b -> bit-identical output.
__global__ __launch_bounds__(256) void attn2c(const float* __restrict__ q, const float* __restrict__ kv,
                                              float* __restrict__ o) {
    int bh = blockIdx.x, b = bh >> 3, h = bh & 7;
    int qg = blockIdx.y;                 // 256 groups of 4 rows
    int t = threadIdx.x, w = t >> 6, l = t & 63;
    int n = qg * 4 + w;
    __shared__ float TB[64 * 36];        // pass1: K[kr][d] stride 36; pass2: Vt[d][c] stride 68 (2176<=2304)
    __shared__ float S[4][1024];         // per-wave score row
    const float scale = 0.17677669529663687f;  // 1/sqrt(32)
    const float* kbase = kv + (size_t)b * 1024 * 512 + h * 32;
    const float* vbase = kbase + 256;
    const float* qrow = q + ((size_t)(b * 1024 + n)) * DMODEL + h * 32;
    float qreg[32];
#pragma unroll
    for (int i = 0; i < 8; i++) {
        float4 q4 = *reinterpret_cast<const float4*>(qrow + i * 4);
        qreg[i * 4] = q4.x; qreg[i * 4 + 1] = q4.y; qreg[i * 4 + 2] = q4.z; qreg[i * 4 + 3] = q4.w;
    }

    // pass 1: scores + per-lane max (lane l owns k = kt*64+l)
    float mx = -1e30f;
    for (int kt = 0; kt < 16; kt++) {
        __syncthreads();
        {   // stage K tile: b128 writes, conflict-free
            int kr = t >> 2, d0 = (t & 3) * 8;
            const float* src = kbase + (size_t)(kt * 64 + kr) * 512 + d0;
            float4 k4 = *reinterpret_cast<const float4*>(src);
            float4 k5 = *reinterpret_cast<const float4*>(src + 4);
            *reinterpret_cast<float4*>(&TB[kr * 36 + d0]) = k4;
            *reinterpret_cast<float4*>(&TB[kr * 36 + d0 + 4]) = k5;
        }
        __syncthreads();
        float s = 0.0f;
#pragma unroll
        for (int j = 0; j < 8; j++) {    // same d-ascending chain as before
            float4 k4 = *reinterpret_cast<float4*>(&TB[l * 36 + j * 4]);
            s += qreg[j * 4] * k4.x; s += qreg[j * 4 + 1] * k4.y;
            s += qreg[j * 4 + 2] * k4.z; s += qreg[j * 4 + 3] * k4.w;
        }
        s *= scale;
        S[w][kt * 64 + l] = s;
        mx = fmaxf(mx, s);
    }
    for (int off = 1; off < 64; off <<= 1) mx = fmaxf(mx, __shfl_xor(mx, off));

    // weights + row sum
    float lsum = 0.0f;
#pragma unroll
    for (int kt = 0; kt < 16; kt++) {
        float e = expf(S[w][kt * 64 + l] - mx);
        S[w][kt * 64 + l] = e;
        lsum += e;
    }
    for (int off = 1; off < 64; off <<= 1) lsum += __shfl_xor(lsum, off);
    float inv = 1.0f / lsum;

    // pass 2: lane l -> dim d=l&31, columns c0..c0+31; V transposed in LDS
    float od = 0.0f;
    int d = l & 31, c0 = (l >> 5) * 32;
    for (int kt = 0; kt < 16; kt++) {
        __syncthreads();
        {   // stage V transposed: Vt[d][kr], thread t: d=t&31, kr = (t>>5)+8i
            int dd = t & 31, kr0 = t >> 5;
#pragma unroll
            for (int i = 0; i < 8; i++) {
                int kr = kr0 + 8 * i;
                TB[dd * 68 + kr] = vbase[(size_t)(kt * 64 + kr) * 512 + dd];
            }
        }
        __syncthreads();
#pragma unroll
        for (int j = 0; j < 8; j++) {    // same c-ascending chain as before
            float4 s4 = *reinterpret_cast<float4*>(&S[w][kt * 64 + c0 + j * 4]);
            float4 v4 = *reinterpret_cast<float4*>(&TB[d * 68 + c0 + j * 4]);
            od += s4.x * v4.x; od += s4.y * v4.y; od += s4.z * v4.z; od += s4.w * v4.w;
        }
    }
    od += __shfl_xor(od, 32);            // merge the two half-range partials
    if (l < 32) o[((size_t)(b * 1024 + n)) * DMODEL + h * 32 + d] = od * inv;
}

// ---------------- K-means (unchanged — proven) ----------------
__global__ __launch_bounds__(256) void km_zero(float* __restrict__ sums, float* __restrict__ counts) {
    int i = blockIdx.x * 256 + threadIdx.x;
    if (i < NCLUST * DMODEL) sums[i] = 0.0f;
    if (i < NCLUST) counts[i] = 0.0f;
}

__global__ __launch_bounds__(256) void km_assign(const float* __restrict__ xf, const float* __restrict__ centers,
                                                 int* __restrict__ labels, float* __restrict__ counts, int do_counts) {
    __shared__ float CsT[DMODEL][NCLUST + 1];
    int t = threadIdx.x;
    for (int i = 0; i < 64; i++) CsT[t][i] = centers[i * DMODEL + t];
    __syncthreads();
    int lane = t & 63, wv = t >> 6;
    float csq = 0.0f;
    for (int d = 0; d < DMODEL; d++) { float c = CsT[d][lane]; csq += c * c; }
    for (int p = 0; p < 4; p++) {
        int i = blockIdx.x * 16 + wv * 4 + p;
        const float* xr = xf + (size_t)i * DMODEL;
        float dot = 0.0f, xsq = 0.0f;
        for (int d = 0; d < DMODEL; d++) { float xv = xr[d]; dot += xv * CsT[d][lane]; xsq += xv * xv; }
        float dist = xsq - 2.0f * dot + csq;
        float best = dist; int bi = lane;
        for (int off = 1; off < 64; off <<= 1) {
            float ov = __shfl_xor(best, off);
            int oi = __shfl_xor(bi, off);
            if (ov < best || (ov == best && oi < bi)) { best = ov; bi = oi; }
        }
        if (lane == 0) {
            labels[i] = bi;
            if (do_counts) atomicAdd(&counts[bi], 1.0f);
        }
    }
}

__global__ __launch_bounds__(256) void km_segsum(const float* __restrict__ xf, const int* __restrict__ labels,
                                                 float* __restrict__ sums) {
    __shared__ float lsum[NCLUST][DMODEL];
    int t = threadIdx.x;
    for (int j = 0; j < NCLUST; j++) lsum[j][t] = 0.0f;
    int base = blockIdx.x * 128;
    for (int p = 0; p < 128; p++) {
        int i = base + p;
        int lab = labels[i];
        lsum[lab][t] += xf[(size_t)i * DMODEL + t];
    }
    for (int j = 0; j < NCLUST; j++) atomicAdd(&sums[j * DMODEL + t], lsum[j][t]);
}

__global__ __launch_bounds__(256) void km_update(float* __restrict__ centers, const float* __restrict__ sums,
                                                 const float* __restrict__ counts) {
    int j = blockIdx.x, d = threadIdx.x;
    float c = counts[j];
    if (c > 0.0f) centers[j * DMODEL + d] = sums[j * DMODEL + d] / fmaxf(c, 1.0f);
}

__global__ __launch_bounds__(256) void nproj(const float* __restrict__ centers, const float* __restrict__ kW,
                                             const float* __restrict__ kb2, float* __restrict__ outc) {
    int idx = blockIdx.x * 256 + threadIdx.x;
    if (idx >= NCLUST * DMODEL) return;
    int row = idx >> 8, col = idx & 255;
    const float* cr = centers + row * DMODEL;
    float acc = 0.0f;
    for (int d = 0; d < DMODEL; d++) acc += cr[d] * kW[(size_t)d * DMODEL + col];
    outc[idx] = acc + kb2[col];
}

__global__ __launch_bounds__(256) void km_gather(const int* __restrict__ labels, const float* __restrict__ outc,
                                                 float* __restrict__ out) {
    int i = blockIdx.x, t = threadIdx.x;
    int lab = labels[i];
    out[(size_t)i * DMODEL + t] = outc[lab * DMODEL + t];
}

extern "C" void kernel_launch(void* const* d_in, const int* in_sizes, int n_in,
                              void* d_out, int out_size, void* d_ws, size_t ws_size,
                              hipStream_t stream) {
    const float* x_in  = (const float*)d_in[0];
    const float* ln1_g = (const float*)d_in[1];
    const float* ln1_b = (const float*)d_in[2];
    const float* Wq    = (const float*)d_in[3];
    const float* Wkv   = (const float*)d_in[4];
    const float* Wo    = (const float*)d_in[5];
    const float* bo    = (const float*)d_in[6];
    const float* ln2_g = (const float*)d_in[7];
    const float* ln2_b = (const float*)d_in[8];
    const float* W1    = (const float*)d_in[9];
    const float* b1    = (const float*)d_in[10];
    const float* W2    = (const float*)d_in[11];
    const float* b2    = (const float*)d_in[12];
    const float* kWp   = (const float*)d_in[13];
    const float* kbp   = (const float*)d_in[14];
    float* out = (float*)d_out;

    const size_t NEEDED = 42173440;
    if (ws_size < NEEDED) {
        hipMemsetAsync(d_out, 0, (size_t)out_size * sizeof(float), stream);
        return;
    }

    char* ws = (char*)d_ws;
    float* xf      = (float*)(ws);              //  8 MB   residual stream (mutable)
    float* xn      = (float*)(ws + 8388608);    //  8 MB   LN output; aliased as attention output
    float* ao      = xn;
    float* qb      = (float*)(ws + 16777216);   //  8 MB
    float* kvb     = (float*)(ws + 25165824);   // 16 MB
    float* hb      = (float*)(ws + 16777216);   // 16 MB   FFN hidden (qb/kvb dead by then)
    float* centers = (float*)(ws + 41943040);   // 64 KB
    float* sums    = (float*)(ws + 42008576);   // 64 KB
    float* counts  = (float*)(ws + 42074112);   // 1 KB region
    int*   labels  = (int*)  (ws + 42075136);   // 32 KB
    float* outc    = (float*)(ws + 42107904);   // 64 KB -> end 42173440

    hipMemcpyAsync(xf, x_in, (size_t)BN * DMODEL * sizeof(float), hipMemcpyDeviceToDevice, stream);

    for (int l = 0; l < 4; l++) {
        ln_wave<<<BN / 4, 256, 0, stream>>>(xf, ln1_g + l * 256, ln1_b + l * 256, xn);
        gemm_big<<<dim3(4, 64), 256, 0, stream>>>(xn, Wq + (size_t)l * 65536, nullptr, nullptr, qb, BN, 256, 256, 0);
        gemm_big<<<dim3(8, 64), 256, 0, stream>>>(xn, Wkv + (size_t)l * 131072, nullptr, nullptr, kvb, BN, 512, 256, 0);
        attn2c<<<dim3(64, 256), 256, 0, stream>>>(qb, kvb, ao);   // ao == xn (xn dead now)
        gemm_big<<<dim3(4, 64), 256, 0, stream>>>(ao, Wo + (size_t)l * 65536, bo + l * 256, xf, xf, BN, 256, 256, 0);
        ln_wave<<<BN / 4, 256, 0, stream>>>(xf, ln2_g + l * 256, ln2_b + l * 256, xn);
        // FFN chunked over rows (2 x 4096) so hidden buffer fits in 16 MB (qb/kvb dead)
        for (int c = 0; c < 2; c++) {
            float* xnc = xn + (size_t)c * 4096 * 256;
            float* xfc = xf + (size_t)c * 4096 * 256;
            gemm_big<<<dim3(16, 32), 256, 0, stream>>>(xnc, W1 + (size_t)l * 262144, b1 + l * 1024, nullptr, hb, 4096, 1024, 256, 1);
            gemm64<<<dim3(4, 64), 256, 0, stream>>>(hb, W2 + (size_t)l * 262144, b2 + l * 256, xfc, xfc, 4096, 256, 1024, 0);
        }
    }

    hipMemcpyAsync(centers, xf, NCLUST * DMODEL * sizeof(float), hipMemcpyDeviceToDevice, stream);
    for (int it = 0; it < 10; it++) {
        km_zero<<<64, 256, 0, stream>>>(sums, counts);
        km_assign<<<512, 256, 0, stream>>>(xf, centers, labels, counts, 1);
        km_segsum<<<64, 256, 0, stream>>>(xf, labels, sums);
        km_update<<<64, 256, 0, stream>>>(centers, sums, counts);
    }
    km_assign<<<512, 256, 0, stream>>>(xf, centers, labels, nullptr, 0);
    nproj<<<64, 256, 0, stream>>>(centers, kWp, kbp, outc);
    km_gather<<<BN, 256, 0, stream>>>(labels, outc, out);
}

// Round 9
// 3798.080 us; speedup vs baseline: 1.1595x; 1.1595x over previous
//
#include <hip/hip_runtime.h>
#include <hip/hip_bf16.h>
#include <math.h>

// Problem constants (B=8, N=1024, D=256, L=4, M=1024, H=8, dh=32, K=64 clusters)
#define BN 8192           // B*N rows
#define DMODEL 256
#define FFN 1024
#define NCLUST 64

// ---------------- LayerNorm: one wave per row, float4 + shuffle reduce, no barriers ----------------
__global__ __launch_bounds__(256) void ln_wave(const float* __restrict__ x, const float* __restrict__ g,
                                               const float* __restrict__ b, float* __restrict__ y) {
    int t = threadIdx.x, w = t >> 6, l = t & 63;
    int row = blockIdx.x * 4 + w;
    const float* xr = x + (size_t)row * DMODEL;
    float4 v = *reinterpret_cast<const float4*>(xr + l * 4);
    float s = v.x + v.y + v.z + v.w;
    for (int off = 1; off < 64; off <<= 1) s += __shfl_xor(s, off);
    float mean = s * (1.0f / 256.0f);
    float4 dv = make_float4(v.x - mean, v.y - mean, v.z - mean, v.w - mean);
    float vs = dv.x * dv.x + dv.y * dv.y + dv.z * dv.z + dv.w * dv.w;
    for (int off = 1; off < 64; off <<= 1) vs += __shfl_xor(vs, off);
    float rs = rsqrtf(vs * (1.0f / 256.0f) + 1e-5f);
    float4 gg = *reinterpret_cast<const float4*>(g + l * 4);
    float4 bb = *reinterpret_cast<const float4*>(b + l * 4);
    float4 out = make_float4(dv.x * rs * gg.x + bb.x, dv.y * rs * gg.y + bb.y,
                             dv.z * rs * gg.z + bb.z, dv.w * rs * gg.w + bb.w);
    *reinterpret_cast<float4*>(y + (size_t)row * DMODEL + l * 4) = out;
}

// ---------------- Tiled GEMM v3: round-7 gemm_t + register prefetch double-buffer ----------------
// Per-output k-chain identical to naive (k0 asc, kk asc) -> bit-identical numerics.
template<int TN>
__global__ __launch_bounds__(256) void gemm_t(const float* __restrict__ A, const float* __restrict__ W,
                                              const float* __restrict__ bias, const float* __restrict__ resid,
                                              float* __restrict__ C, int M, int Nn, int K, int fuse_gelu) {
    constexpr int NW = TN / 16;
    __shared__ float As[16][64];
    __shared__ float Bs[16][TN];
    int t = threadIdx.x, tx = t & 15, ty = t >> 4;
    int m0 = blockIdx.y * 64, n0 = blockIdx.x * TN;
    int mr = t >> 2, kq = (t & 3) * 4;          // A staging coords
    int kkb = t >> 4;                            // B staging row
    int nq = (t & 15) * ((TN == 64) ? 4 : 8);    // B staging cols
    float4 pa, pb0, pb1;
    pa = *reinterpret_cast<const float4*>(A + (size_t)(m0 + mr) * K + kq);
    pb0 = *reinterpret_cast<const float4*>(W + (size_t)kkb * Nn + n0 + nq);
    if (TN == 128) pb1 = *reinterpret_cast<const float4*>(W + (size_t)kkb * Nn + n0 + nq + 4);
    float acc[4][NW] = {};
    for (int k0 = 0; k0 < K; k0 += 16) {
        __syncthreads();   // prior compute finished reading LDS
        As[kq][mr] = pa.x; As[kq + 1][mr] = pa.y; As[kq + 2][mr] = pa.z; As[kq + 3][mr] = pa.w;
        *reinterpret_cast<float4*>(&Bs[kkb][nq]) = pb0;
        if (TN == 128) *reinterpret_cast<float4*>(&Bs[kkb][nq + 4]) = pb1;
        __syncthreads();
        int k1 = k0 + 16;
        if (k1 < K) {      // prefetch next K-block while computing this one
            pa = *reinterpret_cast<const float4*>(A + (size_t)(m0 + mr) * K + k1 + kq);
            pb0 = *reinterpret_cast<const float4*>(W + (size_t)(k1 + kkb) * Nn + n0 + nq);
            if (TN == 128) pb1 = *reinterpret_cast<const float4*>(W + (size_t)(k1 + kkb) * Nn + n0 + nq + 4);
        }
#pragma unroll
        for (int kk = 0; kk < 16; kk++) {
            float4 a4 = *reinterpret_cast<float4*>(&As[kk][ty * 4]);
            float a[4] = {a4.x, a4.y, a4.z, a4.w};
            float bf[NW];
#pragma unroll
            for (int j = 0; j < NW; j += 4) {
                float4 b4 = *reinterpret_cast<float4*>(&Bs[kk][tx * NW + j]);
                bf[j] = b4.x; bf[j + 1] = b4.y; bf[j + 2] = b4.z; bf[j + 3] = b4.w;
            }
#pragma unroll
            for (int i = 0; i < 4; i++)
#pragma unroll
                for (int j = 0; j < NW; j++) acc[i][j] += a[i] * bf[j];
        }
    }
#pragma unroll
    for (int i = 0; i < 4; i++) {
#pragma unroll
        for (int j = 0; j < NW; j++) {
            int row = m0 + ty * 4 + i, col = n0 + tx * NW + j;
            float v = acc[i][j];
            if (bias) v += bias[col];
            if (fuse_gelu) v = 0.5f * v * (1.0f + erff(v * 0.70710678118654752f));
            if (resid) v += resid[(size_t)row * Nn + col];
            C[(size_t)row * Nn + col] = v;
        }
    }
}

// ---------------- Attention v4: scores in registers, lane-owns-its-k PV ----------------
// One wave per q-row. Pass 1: lane l scores k=kt*64+l (d-ascending dot, as proven).
// Softmax via register butterflies (exact max, same exp args as naive).
// Pass 2: lane applies ITS OWN weight to V row l -> no S matrix, no cross-lane LDS reads.
// Final: 64-lane butterfly sum of od[32], wave-local LDS bounce for the coalesced store.
__global__ __launch_bounds__(256) void attn4(const float* __restrict__ q, const float* __restrict__ kv,
                                             float* __restrict__ o) {
    int bh = blockIdx.x, b = bh >> 3, h = bh & 7;
    int qg = blockIdx.y;                 // 256 groups of 4 rows
    int t = threadIdx.x, w = t >> 6, l = t & 63;
    int n = qg * 4 + w;
    __shared__ float T[64 * 33];         // K/V tile, stride 33 -> bank (kr+d)%32, 2-way max (free)
    __shared__ float OS[4][32];          // per-wave output bounce
    const float scale = 0.17677669529663687f;  // 1/sqrt(32)
    const float* kbase = kv + (size_t)b * 1024 * 512 + h * 32;
    const float* vbase = kbase + 256;
    const float* qrow = q + ((size_t)(b * 1024 + n)) * DMODEL + h * 32;
    float qreg[32];
#pragma unroll
    for (int i = 0; i < 8; i++) {
        float4 q4 = *reinterpret_cast<const float4*>(qrow + i * 4);
        qreg[i * 4] = q4.x; qreg[i * 4 + 1] = q4.y; qreg[i * 4 + 2] = q4.z; qreg[i * 4 + 3] = q4.w;
    }
    int kr = t >> 2, d0 = (t & 3) * 8;   // staging coords (same bank-free pattern as attn2b)

    // pass 1: scores -> registers
    float sreg[16];
    for (int kt = 0; kt < 16; kt++) {
        __syncthreads();
        const float* src = kbase + (size_t)(kt * 64 + kr) * 512 + d0;
        float4 k4 = *reinterpret_cast<const float4*>(src);
        float4 k5 = *reinterpret_cast<const float4*>(src + 4);
        float* dst = &T[kr * 33 + d0];
        dst[0] = k4.x; dst[1] = k4.y; dst[2] = k4.z; dst[3] = k4.w;
        dst[4] = k5.x; dst[5] = k5.y; dst[6] = k5.z; dst[7] = k5.w;
        __syncthreads();
        float s = 0.0f;
#pragma unroll
        for (int d = 0; d < 32; d++) s += qreg[d] * T[l * 33 + d];
        sreg[kt] = s * scale;
    }
    float mx = -1e30f;
#pragma unroll
    for (int kt = 0; kt < 16; kt++) mx = fmaxf(mx, sreg[kt]);
    for (int off = 1; off < 64; off <<= 1) mx = fmaxf(mx, __shfl_xor(mx, off));
    float lsum = 0.0f;
#pragma unroll
    for (int kt = 0; kt < 16; kt++) { sreg[kt] = expf(sreg[kt] - mx); lsum += sreg[kt]; }
    for (int off = 1; off < 64; off <<= 1) lsum += __shfl_xor(lsum, off);
    float inv = 1.0f / lsum;

    // pass 2: od[d] += e_own * V[l][d]
    float od[32];
#pragma unroll
    for (int d = 0; d < 32; d++) od[d] = 0.0f;
    for (int kt = 0; kt < 16; kt++) {
        __syncthreads();
        const float* src = vbase + (size_t)(kt * 64 + kr) * 512 + d0;
        float4 v4 = *reinterpret_cast<const float4*>(src);
        float4 v5 = *reinterpret_cast<const float4*>(src + 4);
        float* dst = &T[kr * 33 + d0];
        dst[0] = v4.x; dst[1] = v4.y; dst[2] = v4.z; dst[3] = v4.w;
        dst[4] = v5.x; dst[5] = v5.y; dst[6] = v5.z; dst[7] = v5.w;
        __syncthreads();
        float e = sreg[kt];
#pragma unroll
        for (int d = 0; d < 32; d++) od[d] += e * T[l * 33 + d];
    }
    // 64-lane sum of the 32 partials
    for (int off = 1; off < 64; off <<= 1) {
#pragma unroll
        for (int d = 0; d < 32; d++) od[d] += __shfl_xor(od[d], off);
    }
    if (l == 0) {
#pragma unroll
        for (int d = 0; d < 32; d++) OS[w][d] = od[d];
    }
    // wave-local LDS write->read: in-order within a wave (compiler emits lgkmcnt wait)
    if (l < 32) o[((size_t)(b * 1024 + n)) * DMODEL + h * 32 + l] = OS[w][l] * inv;
}

// ---------------- K-means (unchanged — proven) ----------------
__global__ __launch_bounds__(256) void km_zero(float* __restrict__ sums, float* __restrict__ counts) {
    int i = blockIdx.x * 256 + threadIdx.x;
    if (i < NCLUST * DMODEL) sums[i] = 0.0f;
    if (i < NCLUST) counts[i] = 0.0f;
}

__global__ __launch_bounds__(256) void km_assign(const float* __restrict__ xf, const float* __restrict__ centers,
                                                 int* __restrict__ labels, float* __restrict__ counts, int do_counts) {
    __shared__ float CsT[DMODEL][NCLUST + 1];
    int t = threadIdx.x;
    for (int i = 0; i < 64; i++) CsT[t][i] = centers[i * DMODEL + t];
    __syncthreads();
    int lane = t & 63, wv = t >> 6;
    float csq = 0.0f;
    for (int d = 0; d < DMODEL; d++) { float c = CsT[d][lane]; csq += c * c; }
    for (int p = 0; p < 4; p++) {
        int i = blockIdx.x * 16 + wv * 4 + p;
        const float* xr = xf + (size_t)i * DMODEL;
        float dot = 0.0f, xsq = 0.0f;
        for (int d = 0; d < DMODEL; d++) { float xv = xr[d]; dot += xv * CsT[d][lane]; xsq += xv * xv; }
        float dist = xsq - 2.0f * dot + csq;
        float best = dist; int bi = lane;
        for (int off = 1; off < 64; off <<= 1) {
            float ov = __shfl_xor(best, off);
            int oi = __shfl_xor(bi, off);
            if (ov < best || (ov == best && oi < bi)) { best = ov; bi = oi; }
        }
        if (lane == 0) {
            labels[i] = bi;
            if (do_counts) atomicAdd(&counts[bi], 1.0f);
        }
    }
}

__global__ __launch_bounds__(256) void km_segsum(const float* __restrict__ xf, const int* __restrict__ labels,
                                                 float* __restrict__ sums) {
    __shared__ float lsum[NCLUST][DMODEL];
    int t = threadIdx.x;
    for (int j = 0; j < NCLUST; j++) lsum[j][t] = 0.0f;
    int base = blockIdx.x * 128;
    for (int p = 0; p < 128; p++) {
        int i = base + p;
        int lab = labels[i];
        lsum[lab][t] += xf[(size_t)i * DMODEL + t];
    }
    for (int j = 0; j < NCLUST; j++) atomicAdd(&sums[j * DMODEL + t], lsum[j][t]);
}

__global__ __launch_bounds__(256) void km_update(float* __restrict__ centers, const float* __restrict__ sums,
                                                 const float* __restrict__ counts) {
    int j = blockIdx.x, d = threadIdx.x;
    float c = counts[j];
    if (c > 0.0f) centers[j * DMODEL + d] = sums[j * DMODEL + d] / fmaxf(c, 1.0f);
}

__global__ __launch_bounds__(256) void nproj(const float* __restrict__ centers, const float* __restrict__ kW,
                                             const float* __restrict__ kb2, float* __restrict__ outc) {
    int idx = blockIdx.x * 256 + threadIdx.x;
    if (idx >= NCLUST * DMODEL) return;
    int row = idx >> 8, col = idx & 255;
    const float* cr = centers + row * DMODEL;
    float acc = 0.0f;
    for (int d = 0; d < DMODEL; d++) acc += cr[d] * kW[(size_t)d * DMODEL + col];
    outc[idx] = acc + kb2[col];
}

__global__ __launch_bounds__(256) void km_gather(const int* __restrict__ labels, const float* __restrict__ outc,
                                                 float* __restrict__ out) {
    int i = blockIdx.x, t = threadIdx.x;
    int lab = labels[i];
    out[(size_t)i * DMODEL + t] = outc[lab * DMODEL + t];
}

extern "C" void kernel_launch(void* const* d_in, const int* in_sizes, int n_in,
                              void* d_out, int out_size, void* d_ws, size_t ws_size,
                              hipStream_t stream) {
    const float* x_in  = (const float*)d_in[0];
    const float* ln1_g = (const float*)d_in[1];
    const float* ln1_b = (const float*)d_in[2];
    const float* Wq    = (const float*)d_in[3];
    const float* Wkv   = (const float*)d_in[4];
    const float* Wo    = (const float*)d_in[5];
    const float* bo    = (const float*)d_in[6];
    const float* ln2_g = (const float*)d_in[7];
    const float* ln2_b = (const float*)d_in[8];
    const float* W1    = (const float*)d_in[9];
    const float* b1    = (const float*)d_in[10];
    const float* W2    = (const float*)d_in[11];
    const float* b2    = (const float*)d_in[12];
    const float* kWp   = (const float*)d_in[13];
    const float* kbp   = (const float*)d_in[14];
    float* out = (float*)d_out;

    const size_t NEEDED = 42173440;
    if (ws_size < NEEDED) {
        hipMemsetAsync(d_out, 0, (size_t)out_size * sizeof(float), stream);
        return;
    }

    char* ws = (char*)d_ws;
    float* xf      = (float*)(ws);              //  8 MB   residual stream (mutable)
    float* xn      = (float*)(ws + 8388608);    //  8 MB   LN output; aliased as attention output
    float* ao      = xn;
    float* qb      = (float*)(ws + 16777216);   //  8 MB
    float* kvb     = (float*)(ws + 25165824);   // 16 MB
    float* hb      = (float*)(ws + 16777216);   // 16 MB   FFN hidden (qb/kvb dead by then)
    float* centers = (float*)(ws + 41943040);   // 64 KB
    float* sums    = (float*)(ws + 42008576);   // 64 KB
    float* counts  = (float*)(ws + 42074112);   // 1 KB region
    int*   labels  = (int*)  (ws + 42075136);   // 32 KB
    float* outc    = (float*)(ws + 42107904);   // 64 KB -> end 42173440

    hipMemcpyAsync(xf, x_in, (size_t)BN * DMODEL * sizeof(float), hipMemcpyDeviceToDevice, stream);

    for (int l = 0; l < 4; l++) {
        ln_wave<<<BN / 4, 256, 0, stream>>>(xf, ln1_g + l * 256, ln1_b + l * 256, xn);
        gemm_t<64><<<dim3(4, 128), 256, 0, stream>>>(xn, Wq + (size_t)l * 65536, nullptr, nullptr, qb, BN, 256, 256, 0);
        gemm_t<128><<<dim3(4, 128), 256, 0, stream>>>(xn, Wkv + (size_t)l * 131072, nullptr, nullptr, kvb, BN, 512, 256, 0);
        attn4<<<dim3(64, 256), 256, 0, stream>>>(qb, kvb, ao);   // ao == xn (xn dead now)
        gemm_t<64><<<dim3(4, 128), 256, 0, stream>>>(ao, Wo + (size_t)l * 65536, bo + l * 256, xf, xf, BN, 256, 256, 0);
        ln_wave<<<BN / 4, 256, 0, stream>>>(xf, ln2_g + l * 256, ln2_b + l * 256, xn);
        // FFN chunked over rows (2 x 4096) so hidden buffer fits in 16 MB (qb/kvb dead)
        for (int c = 0; c < 2; c++) {
            float* xnc = xn + (size_t)c * 4096 * 256;
            float* xfc = xf + (size_t)c * 4096 * 256;
            gemm_t<128><<<dim3(8, 64), 256, 0, stream>>>(xnc, W1 + (size_t)l * 262144, b1 + l * 1024, nullptr, hb, 4096, 1024, 256, 1);
            gemm_t<64><<<dim3(4, 64), 256, 0, stream>>>(hb, W2 + (size_t)l * 262144, b2 + l * 256, xfc, xfc, 4096, 256, 1024, 0);
        }
    }

    hipMemcpyAsync(centers, xf, NCLUST * DMODEL * sizeof(float), hipMemcpyDeviceToDevice, stream);
    for (int it = 0; it < 10; it++) {
        km_zero<<<64, 256, 0, stream>>>(sums, counts);
        km_assign<<<512, 256, 0, stream>>>(xf, centers, labels, counts, 1);
        km_segsum<<<64, 256, 0, stream>>>(xf, labels, sums);
        km_update<<<64, 256, 0, stream>>>(centers, sums, counts);
    }
    km_assign<<<512, 256, 0, stream>>>(xf, centers, labels, nullptr, 0);
    nproj<<<64, 256, 0, stream>>>(centers, kWp, kbp, outc);
    km_gather<<<BN, 256, 0, stream>>>(labels, outc, out);
}

// Round 10
// 3632.444 us; speedup vs baseline: 1.2124x; 1.0456x over previous
//
#include <hip/hip_runtime.h>
#include <hip/hip_bf16.h>
#include <math.h>

// Problem constants (B=8, N=1024, D=256, L=4, M=1024, H=8, dh=32, K=64 clusters)
#define BN 8192           // B*N rows
#define DMODEL 256
#define FFN 1024
#define NCLUST 64

// ---------------- LayerNorm: one wave per row, float4 + shuffle reduce (proven r7) ----------------
__global__ __launch_bounds__(256) void ln_wave(const float* __restrict__ x, const float* __restrict__ g,
                                               const float* __restrict__ b, float* __restrict__ y) {
    int t = threadIdx.x, w = t >> 6, l = t & 63;
    int row = blockIdx.x * 4 + w;
    const float* xr = x + (size_t)row * DMODEL;
    float4 v = *reinterpret_cast<const float4*>(xr + l * 4);
    float s = v.x + v.y + v.z + v.w;
    for (int off = 1; off < 64; off <<= 1) s += __shfl_xor(s, off);
    float mean = s * (1.0f / 256.0f);
    float4 dv = make_float4(v.x - mean, v.y - mean, v.z - mean, v.w - mean);
    float vs = dv.x * dv.x + dv.y * dv.y + dv.z * dv.z + dv.w * dv.w;
    for (int off = 1; off < 64; off <<= 1) vs += __shfl_xor(vs, off);
    float rs = rsqrtf(vs * (1.0f / 256.0f) + 1e-5f);
    float4 gg = *reinterpret_cast<const float4*>(g + l * 4);
    float4 bb = *reinterpret_cast<const float4*>(b + l * 4);
    float4 out = make_float4(dv.x * rs * gg.x + bb.x, dv.y * rs * gg.y + bb.y,
                             dv.z * rs * gg.z + bb.z, dv.w * rs * gg.w + bb.w);
    *reinterpret_cast<float4*>(y + (size_t)row * DMODEL + l * 4) = out;
}

// ---------------- GEMM-B: 128x64 tile, BK=16, 8x4 microtile, register prefetch ----------------
// k-chain identical to naive (k0 asc, kk asc). All LDS patterns <=2-way banks.
__global__ __launch_bounds__(256) void gemm_b(const float* __restrict__ A, const float* __restrict__ W,
                                              const float* __restrict__ bias, const float* __restrict__ resid,
                                              float* __restrict__ C, int M, int Nn, int K, int fuse_gelu) {
    __shared__ float As[16][128];
    __shared__ float Bs[16][64];
    int t = threadIdx.x, tx = t & 15, ty = t >> 4;
    int m0 = blockIdx.y * 128, n0 = blockIdx.x * 64;
    int mr = t >> 1, kq = (t & 1) * 8;   // A staging: 8 floats/thread
    int kkb = t >> 4, nq = (t & 15) * 4; // B staging
    float4 pa0, pa1, pb;
    {
        const float* src = A + (size_t)(m0 + mr) * K + kq;
        pa0 = *reinterpret_cast<const float4*>(src);
        pa1 = *reinterpret_cast<const float4*>(src + 4);
        pb  = *reinterpret_cast<const float4*>(W + (size_t)kkb * Nn + n0 + nq);
    }
    float acc[8][4] = {};
    for (int k0 = 0; k0 < K; k0 += 16) {
        __syncthreads();
        As[kq][mr] = pa0.x; As[kq + 1][mr] = pa0.y; As[kq + 2][mr] = pa0.z; As[kq + 3][mr] = pa0.w;
        As[kq + 4][mr] = pa1.x; As[kq + 5][mr] = pa1.y; As[kq + 6][mr] = pa1.z; As[kq + 7][mr] = pa1.w;
        *reinterpret_cast<float4*>(&Bs[kkb][nq]) = pb;
        __syncthreads();
        int k1 = k0 + 16;
        if (k1 < K) {
            const float* src = A + (size_t)(m0 + mr) * K + k1 + kq;
            pa0 = *reinterpret_cast<const float4*>(src);
            pa1 = *reinterpret_cast<const float4*>(src + 4);
            pb  = *reinterpret_cast<const float4*>(W + (size_t)(k1 + kkb) * Nn + n0 + nq);
        }
#pragma unroll
        for (int kk = 0; kk < 16; kk++) {
            float4 a0 = *reinterpret_cast<float4*>(&As[kk][ty * 8]);
            float4 a1 = *reinterpret_cast<float4*>(&As[kk][ty * 8 + 4]);
            float4 b4 = *reinterpret_cast<float4*>(&Bs[kk][tx * 4]);
            float a[8] = {a0.x, a0.y, a0.z, a0.w, a1.x, a1.y, a1.z, a1.w};
            float bf[4] = {b4.x, b4.y, b4.z, b4.w};
#pragma unroll
            for (int i = 0; i < 8; i++)
#pragma unroll
                for (int j = 0; j < 4; j++) acc[i][j] += a[i] * bf[j];
        }
    }
#pragma unroll
    for (int i = 0; i < 8; i++) {
        int row = m0 + ty * 8 + i, col = n0 + tx * 4;
        float4 v = make_float4(acc[i][0], acc[i][1], acc[i][2], acc[i][3]);
        if (bias) { float4 bb = *reinterpret_cast<const float4*>(bias + col);
                    v.x += bb.x; v.y += bb.y; v.z += bb.z; v.w += bb.w; }
        if (fuse_gelu) {
            v.x = 0.5f * v.x * (1.0f + erff(v.x * 0.70710678118654752f));
            v.y = 0.5f * v.y * (1.0f + erff(v.y * 0.70710678118654752f));
            v.z = 0.5f * v.z * (1.0f + erff(v.z * 0.70710678118654752f));
            v.w = 0.5f * v.w * (1.0f + erff(v.w * 0.70710678118654752f));
        }
        if (resid) { float4 rr = *reinterpret_cast<const float4*>(resid + (size_t)row * Nn + col);
                     v.x += rr.x; v.y += rr.y; v.z += rr.z; v.w += rr.w; }
        *reinterpret_cast<float4*>(C + (size_t)row * Nn + col) = v;
    }
}

// ---------------- GEMM-T: 64x64 tile, 4x4, prefetch, As padded stride 68 (bank fix) ----------------
__global__ __launch_bounds__(256) void gemm_t(const float* __restrict__ A, const float* __restrict__ W,
                                              const float* __restrict__ bias, const float* __restrict__ resid,
                                              float* __restrict__ C, int M, int Nn, int K, int fuse_gelu) {
    __shared__ float As[16][68];
    __shared__ float Bs[16][64];
    int t = threadIdx.x, tx = t & 15, ty = t >> 4;
    int m0 = blockIdx.y * 64, n0 = blockIdx.x * 64;
    int mr = t >> 2, kq = (t & 3) * 4;
    int kkb = t >> 4, nq = (t & 15) * 4;
    float4 pa, pb;
    pa = *reinterpret_cast<const float4*>(A + (size_t)(m0 + mr) * K + kq);
    pb = *reinterpret_cast<const float4*>(W + (size_t)kkb * Nn + n0 + nq);
    float acc[4][4] = {};
    for (int k0 = 0; k0 < K; k0 += 16) {
        __syncthreads();
        As[kq][mr] = pa.x; As[kq + 1][mr] = pa.y; As[kq + 2][mr] = pa.z; As[kq + 3][mr] = pa.w;
        *reinterpret_cast<float4*>(&Bs[kkb][nq]) = pb;
        __syncthreads();
        int k1 = k0 + 16;
        if (k1 < K) {
            pa = *reinterpret_cast<const float4*>(A + (size_t)(m0 + mr) * K + k1 + kq);
            pb = *reinterpret_cast<const float4*>(W + (size_t)(k1 + kkb) * Nn + n0 + nq);
        }
#pragma unroll
        for (int kk = 0; kk < 16; kk++) {
            float4 a4 = *reinterpret_cast<float4*>(&As[kk][ty * 4]);
            float4 b4 = *reinterpret_cast<float4*>(&Bs[kk][tx * 4]);
            float a[4] = {a4.x, a4.y, a4.z, a4.w};
            float bf[4] = {b4.x, b4.y, b4.z, b4.w};
#pragma unroll
            for (int i = 0; i < 4; i++)
#pragma unroll
                for (int j = 0; j < 4; j++) acc[i][j] += a[i] * bf[j];
        }
    }
#pragma unroll
    for (int i = 0; i < 4; i++) {
#pragma unroll
        for (int j = 0; j < 4; j++) {
            int row = m0 + ty * 4 + i, col = n0 + tx * 4 + j;
            float v = acc[i][j];
            if (bias) v += bias[col];
            if (fuse_gelu) v = 0.5f * v * (1.0f + erff(v * 0.70710678118654752f));
            if (resid) v += resid[(size_t)row * Nn + col];
            C[(size_t)row * Nn + col] = v;
        }
    }
}

// ---------------- Attention v2b (proven r7, 473 us) ----------------
__global__ __launch_bounds__(256) void attn2b(const float* __restrict__ q, const float* __restrict__ kv,
                                              float* __restrict__ o) {
    int bh = blockIdx.x, b = bh >> 3, h = bh & 7;
    int qg = blockIdx.y;
    int t = threadIdx.x, w = t >> 6, l = t & 63;
    int n = qg * 4 + w;
    __shared__ float T[64][33];
    __shared__ float S[4][1024];
    const float scale = 0.17677669529663687f;  // 1/sqrt(32)
    const float* kbase = kv + (size_t)b * 1024 * 512 + h * 32;
    const float* vbase = kbase + 256;
    const float* qrow = q + ((size_t)(b * 1024 + n)) * DMODEL + h * 32;
    float qreg[32];
#pragma unroll
    for (int d = 0; d < 32; d++) qreg[d] = qrow[d];

    float mx = -1e30f;
    for (int kt = 0; kt < 16; kt++) {
        __syncthreads();
#pragma unroll
        for (int i = 0; i < 8; i++) {
            int idx = t * 8 + i; int kr = idx >> 5, d = idx & 31;
            T[kr][d] = kbase[(size_t)(kt * 64 + kr) * 512 + d];
        }
        __syncthreads();
        float s = 0.0f;
#pragma unroll
        for (int d = 0; d < 32; d++) s += qreg[d] * T[l][d];
        s *= scale;
        S[w][kt * 64 + l] = s;
        mx = fmaxf(mx, s);
    }
    for (int off = 1; off < 64; off <<= 1) mx = fmaxf(mx, __shfl_xor(mx, off));

    float lsum = 0.0f;
#pragma unroll
    for (int kt = 0; kt < 16; kt++) {
        float e = expf(S[w][kt * 64 + l] - mx);
        S[w][kt * 64 + l] = e;
        lsum += e;
    }
    for (int off = 1; off < 64; off <<= 1) lsum += __shfl_xor(lsum, off);
    float inv = 1.0f / lsum;

    float od = 0.0f;
    int d = l & 31, c0 = (l >> 5) * 32;
    for (int kt = 0; kt < 16; kt++) {
        __syncthreads();
#pragma unroll
        for (int i = 0; i < 8; i++) {
            int idx = t * 8 + i; int kr = idx >> 5, dd = idx & 31;
            T[kr][dd] = vbase[(size_t)(kt * 64 + kr) * 512 + dd];
        }
        __syncthreads();
#pragma unroll 8
        for (int cc = 0; cc < 32; cc++) {
            int c = c0 + cc;
            od += S[w][kt * 64 + c] * T[c][d];
        }
    }
    od += __shfl_xor(od, 32);
    if (l < 32) o[((size_t)(b * 1024 + n)) * DMODEL + h * 32 + d] = od * inv;
}

// ---------------- K-means v2: dist-GEMM + fused argmin/segsum + fused update ----------------
__global__ __launch_bounds__(256) void km_zero0(float* __restrict__ sums, float* __restrict__ counts) {
    int i = blockIdx.x * 256 + threadIdx.x;
    if (i < NCLUST * DMODEL) sums[i] = 0.0f;
    if (i < NCLUST) counts[i] = 0.0f;
}

// csq[j] = sum_d centers[j][d]^2  (one wave per center)
__global__ __launch_bounds__(64) void csq_k(const float* __restrict__ centers, float* __restrict__ csq) {
    int j = blockIdx.x, l = threadIdx.x;
    float4 c4 = *reinterpret_cast<const float4*>(centers + j * DMODEL + l * 4);
    float s = c4.x * c4.x + c4.y * c4.y + c4.z * c4.z + c4.w * c4.w;
    for (int off = 1; off < 64; off <<= 1) s += __shfl_xor(s, off);
    if (l == 0) csq[j] = s;
}

// dot[i][j] = sum_d xf[i][d]*centers[j][d] ; 64x64 tile, k-chain bit-identical to proven km_assign
__global__ __launch_bounds__(256) void km_dist(const float* __restrict__ A, const float* __restrict__ Cn,
                                               float* __restrict__ dot) {
    __shared__ float As[16][68];
    __shared__ float Bs[16][64];
    int t = threadIdx.x, tx = t & 15, ty = t >> 4;
    int m0 = blockIdx.x * 64;
    int mr = t >> 2, kq = (t & 3) * 4;
    int jb = t & 63, kb = (t >> 6) * 4;
    float acc[4][4] = {};
    for (int k0 = 0; k0 < 256; k0 += 16) {
        __syncthreads();
        {
            float4 a4 = *reinterpret_cast<const float4*>(A + (size_t)(m0 + mr) * DMODEL + k0 + kq);
            As[kq][mr] = a4.x; As[kq + 1][mr] = a4.y; As[kq + 2][mr] = a4.z; As[kq + 3][mr] = a4.w;
        }
        {   // Bs[kk][j] = centers[j][k0+kk]
            float4 c4 = *reinterpret_cast<const float4*>(Cn + (size_t)jb * DMODEL + k0 + kb);
            Bs[kb][jb] = c4.x; Bs[kb + 1][jb] = c4.y; Bs[kb + 2][jb] = c4.z; Bs[kb + 3][jb] = c4.w;
        }
        __syncthreads();
#pragma unroll
        for (int kk = 0; kk < 16; kk++) {
            float4 a4 = *reinterpret_cast<float4*>(&As[kk][ty * 4]);
            float4 b4 = *reinterpret_cast<float4*>(&Bs[kk][tx * 4]);
            float a[4] = {a4.x, a4.y, a4.z, a4.w};
            float bf[4] = {b4.x, b4.y, b4.z, b4.w};
#pragma unroll
            for (int i = 0; i < 4; i++)
#pragma unroll
                for (int j = 0; j < 4; j++) acc[i][j] += a[i] * bf[j];
        }
    }
#pragma unroll
    for (int i = 0; i < 4; i++)
#pragma unroll
        for (int j = 0; j < 4; j++)
            dot[(size_t)(m0 + ty * 4 + i) * NCLUST + tx * 4 + j] = acc[i][j];
}

// phase A: argmin per point (lane-per-center, proven comparator); phase B: segsum (proven layout)
__global__ __launch_bounds__(256) void km_argmin_segsum(const float* __restrict__ dot, const float* __restrict__ csq,
                                                        const float* __restrict__ xf, int* __restrict__ labels,
                                                        float* __restrict__ counts, float* __restrict__ sums,
                                                        int do_seg) {
    __shared__ float lsum[NCLUST][DMODEL];
    __shared__ int lab_s[128];
    int t = threadIdx.x, w = t >> 6, l = t & 63;
    int base = blockIdx.x * 128;
    float cs = csq[l];
    for (int p = 0; p < 32; p++) {
        int i = base + w * 32 + p;
        float val = cs - 2.0f * dot[(size_t)i * NCLUST + l];
        float best = val; int bi = l;
        for (int off = 1; off < 64; off <<= 1) {
            float ov = __shfl_xor(best, off);
            int oi = __shfl_xor(bi, off);
            if (ov < best || (ov == best && oi < bi)) { best = ov; bi = oi; }
        }
        if (l == 0) {
            labels[i] = bi;
            lab_s[w * 32 + p] = bi;
            if (do_seg) atomicAdd(&counts[bi], 1.0f);
        }
    }
    if (!do_seg) return;
    for (int j = 0; j < NCLUST; j++) lsum[j][t] = 0.0f;
    __syncthreads();
    for (int p = 0; p < 128; p++) {
        int lab = lab_s[p];
        lsum[lab][t] += xf[(size_t)(base + p) * DMODEL + t];
    }
    for (int j = 0; j < NCLUST; j++) atomicAdd(&sums[j * DMODEL + t], lsum[j][t]);
}

// update centers, compute csq, re-zero sums/counts for the next iteration
__global__ __launch_bounds__(256) void km_update_zero(float* __restrict__ centers, float* __restrict__ sums,
                                                      float* __restrict__ counts, float* __restrict__ csq) {
    __shared__ float red[256];
    int j = blockIdx.x, d = threadIdx.x;
    float c = counts[j];
    float cv = centers[j * DMODEL + d];
    if (c > 0.0f) cv = sums[j * DMODEL + d] / fmaxf(c, 1.0f);
    centers[j * DMODEL + d] = cv;
    red[d] = cv * cv;
    __syncthreads();
    for (int off = 128; off; off >>= 1) { if (d < off) red[d] += red[d + off]; __syncthreads(); }
    if (d == 0) { csq[j] = red[0]; counts[j] = 0.0f; }
    sums[j * DMODEL + d] = 0.0f;
}

__global__ __launch_bounds__(256) void nproj(const float* __restrict__ centers, const float* __restrict__ kW,
                                             const float* __restrict__ kb2, float* __restrict__ outc) {
    int idx = blockIdx.x * 256 + threadIdx.x;
    if (idx >= NCLUST * DMODEL) return;
    int row = idx >> 8, col = idx & 255;
    const float* cr = centers + row * DMODEL;
    float acc = 0.0f;
    for (int d = 0; d < DMODEL; d++) acc += cr[d] * kW[(size_t)d * DMODEL + col];
    outc[idx] = acc + kb2[col];
}

__global__ __launch_bounds__(256) void km_gather(const int* __restrict__ labels, const float* __restrict__ outc,
                                                 float* __restrict__ out) {
    int i = blockIdx.x, t = threadIdx.x;
    int lab = labels[i];
    out[(size_t)i * DMODEL + t] = outc[lab * DMODEL + t];
}

extern "C" void kernel_launch(void* const* d_in, const int* in_sizes, int n_in,
                              void* d_out, int out_size, void* d_ws, size_t ws_size,
                              hipStream_t stream) {
    const float* x_in  = (const float*)d_in[0];
    const float* ln1_g = (const float*)d_in[1];
    const float* ln1_b = (const float*)d_in[2];
    const float* Wq    = (const float*)d_in[3];
    const float* Wkv   = (const float*)d_in[4];
    const float* Wo    = (const float*)d_in[5];
    const float* bo    = (const float*)d_in[6];
    const float* ln2_g = (const float*)d_in[7];
    const float* ln2_b = (const float*)d_in[8];
    const float* W1    = (const float*)d_in[9];
    const float* b1    = (const float*)d_in[10];
    const float* W2    = (const float*)d_in[11];
    const float* b2    = (const float*)d_in[12];
    const float* kWp   = (const float*)d_in[13];
    const float* kbp   = (const float*)d_in[14];
    float* out = (float*)d_out;

    const size_t NEEDED = 42173440;
    if (ws_size < NEEDED) {
        hipMemsetAsync(d_out, 0, (size_t)out_size * sizeof(float), stream);
        return;
    }

    char* ws = (char*)d_ws;
    float* xf      = (float*)(ws);              //  8 MB   residual stream (mutable)
    float* xn      = (float*)(ws + 8388608);    //  8 MB   LN output; aliased as attention output
    float* ao      = xn;
    float* qb      = (float*)(ws + 16777216);   //  8 MB
    float* kvb     = (float*)(ws + 25165824);   // 16 MB
    float* hb      = (float*)(ws + 16777216);   // 16 MB   FFN hidden (qb/kvb dead by then)
    float* dotb    = qb;                        //  2 MB   kmeans dot matrix (qb dead)
    float* centers = (float*)(ws + 41943040);   // 64 KB
    float* sums    = (float*)(ws + 42008576);   // 64 KB
    float* counts  = (float*)(ws + 42074112);   // 256 B
    float* csqb    = (float*)(ws + 42074368);   // 256 B
    int*   labels  = (int*)  (ws + 42075136);   // 32 KB
    float* outc    = (float*)(ws + 42107904);   // 64 KB -> end 42173440

    hipMemcpyAsync(xf, x_in, (size_t)BN * DMODEL * sizeof(float), hipMemcpyDeviceToDevice, stream);

    for (int l = 0; l < 4; l++) {
        ln_wave<<<BN / 4, 256, 0, stream>>>(xf, ln1_g + l * 256, ln1_b + l * 256, xn);
        gemm_b<<<dim3(4, 64), 256, 0, stream>>>(xn, Wq + (size_t)l * 65536, nullptr, nullptr, qb, BN, 256, 256, 0);
        gemm_b<<<dim3(8, 64), 256, 0, stream>>>(xn, Wkv + (size_t)l * 131072, nullptr, nullptr, kvb, BN, 512, 256, 0);
        attn2b<<<dim3(64, 256), 256, 0, stream>>>(qb, kvb, ao);   // ao == xn (xn dead now)
        gemm_b<<<dim3(4, 64), 256, 0, stream>>>(ao, Wo + (size_t)l * 65536, bo + l * 256, xf, xf, BN, 256, 256, 0);
        ln_wave<<<BN / 4, 256, 0, stream>>>(xf, ln2_g + l * 256, ln2_b + l * 256, xn);
        // FFN chunked over rows (2 x 4096) so hidden buffer fits in 16 MB (qb/kvb dead)
        for (int c = 0; c < 2; c++) {
            float* xnc = xn + (size_t)c * 4096 * 256;
            float* xfc = xf + (size_t)c * 4096 * 256;
            gemm_b<<<dim3(16, 32), 256, 0, stream>>>(xnc, W1 + (size_t)l * 262144, b1 + l * 1024, nullptr, hb, 4096, 1024, 256, 1);
            gemm_t<<<dim3(4, 64), 256, 0, stream>>>(hb, W2 + (size_t)l * 262144, b2 + l * 256, xfc, xfc, 4096, 256, 1024, 0);
        }
    }

    hipMemcpyAsync(centers, xf, NCLUST * DMODEL * sizeof(float), hipMemcpyDeviceToDevice, stream);
    km_zero0<<<64, 256, 0, stream>>>(sums, counts);
    csq_k<<<64, 64, 0, stream>>>(centers, csqb);
    for (int it = 0; it < 10; it++) {
        km_dist<<<128, 256, 0, stream>>>(xf, centers, dotb);
        km_argmin_segsum<<<64, 256, 0, stream>>>(dotb, csqb, xf, labels, counts, sums, 1);
        km_update_zero<<<64, 256, 0, stream>>>(centers, sums, counts, csqb);
    }
    km_dist<<<128, 256, 0, stream>>>(xf, centers, dotb);
    km_argmin_segsum<<<64, 256, 0, stream>>>(dotb, csqb, xf, labels, counts, sums, 0);
    nproj<<<64, 256, 0, stream>>>(centers, kWp, kbp, outc);
    km_gather<<<BN, 256, 0, stream>>>(labels, outc, out);
}

// Round 11
// 2889.749 us; speedup vs baseline: 1.5239x; 1.2570x over previous
//
#include <hip/hip_runtime.h>
#include <hip/hip_bf16.h>
#include <math.h>

// Problem constants (B=8, N=1024, D=256, L=4, M=1024, H=8, dh=32, K=64 clusters)
#define BN 8192           // B*N rows
#define DMODEL 256
#define FFN 1024
#define NCLUST 64

// ---------------- LayerNorm: one wave per row, float4 + shuffle reduce (proven r7) ----------------
__global__ __launch_bounds__(256) void ln_wave(const float* __restrict__ x, const float* __restrict__ g,
                                               const float* __restrict__ b, float* __restrict__ y) {
    int t = threadIdx.x, w = t >> 6, l = t & 63;
    int row = blockIdx.x * 4 + w;
    const float* xr = x + (size_t)row * DMODEL;
    float4 v = *reinterpret_cast<const float4*>(xr + l * 4);
    float s = v.x + v.y + v.z + v.w;
    for (int off = 1; off < 64; off <<= 1) s += __shfl_xor(s, off);
    float mean = s * (1.0f / 256.0f);
    float4 dv = make_float4(v.x - mean, v.y - mean, v.z - mean, v.w - mean);
    float vs = dv.x * dv.x + dv.y * dv.y + dv.z * dv.z + dv.w * dv.w;
    for (int off = 1; off < 64; off <<= 1) vs += __shfl_xor(vs, off);
    float rs = rsqrtf(vs * (1.0f / 256.0f) + 1e-5f);
    float4 gg = *reinterpret_cast<const float4*>(g + l * 4);
    float4 bb = *reinterpret_cast<const float4*>(b + l * 4);
    float4 out = make_float4(dv.x * rs * gg.x + bb.x, dv.y * rs * gg.y + bb.y,
                             dv.z * rs * gg.z + bb.z, dv.w * rs * gg.w + bb.w);
    *reinterpret_cast<float4*>(y + (size_t)row * DMODEL + l * 4) = out;
}

// ---------------- GEMM-B: 128x64 tile, BK=16, 8x4 microtile, register prefetch (proven r10) ----------------
__global__ __launch_bounds__(256) void gemm_b(const float* __restrict__ A, const float* __restrict__ W,
                                              const float* __restrict__ bias, const float* __restrict__ resid,
                                              float* __restrict__ C, int M, int Nn, int K, int fuse_gelu) {
    __shared__ float As[16][128];
    __shared__ float Bs[16][64];
    int t = threadIdx.x, tx = t & 15, ty = t >> 4;
    int m0 = blockIdx.y * 128, n0 = blockIdx.x * 64;
    int mr = t >> 1, kq = (t & 1) * 8;
    int kkb = t >> 4, nq = (t & 15) * 4;
    float4 pa0, pa1, pb;
    {
        const float* src = A + (size_t)(m0 + mr) * K + kq;
        pa0 = *reinterpret_cast<const float4*>(src);
        pa1 = *reinterpret_cast<const float4*>(src + 4);
        pb  = *reinterpret_cast<const float4*>(W + (size_t)kkb * Nn + n0 + nq);
    }
    float acc[8][4] = {};
    for (int k0 = 0; k0 < K; k0 += 16) {
        __syncthreads();
        As[kq][mr] = pa0.x; As[kq + 1][mr] = pa0.y; As[kq + 2][mr] = pa0.z; As[kq + 3][mr] = pa0.w;
        As[kq + 4][mr] = pa1.x; As[kq + 5][mr] = pa1.y; As[kq + 6][mr] = pa1.z; As[kq + 7][mr] = pa1.w;
        *reinterpret_cast<float4*>(&Bs[kkb][nq]) = pb;
        __syncthreads();
        int k1 = k0 + 16;
        if (k1 < K) {
            const float* src = A + (size_t)(m0 + mr) * K + k1 + kq;
            pa0 = *reinterpret_cast<const float4*>(src);
            pa1 = *reinterpret_cast<const float4*>(src + 4);
            pb  = *reinterpret_cast<const float4*>(W + (size_t)(k1 + kkb) * Nn + n0 + nq);
        }
#pragma unroll
        for (int kk = 0; kk < 16; kk++) {
            float4 a0 = *reinterpret_cast<float4*>(&As[kk][ty * 8]);
            float4 a1 = *reinterpret_cast<float4*>(&As[kk][ty * 8 + 4]);
            float4 b4 = *reinterpret_cast<float4*>(&Bs[kk][tx * 4]);
            float a[8] = {a0.x, a0.y, a0.z, a0.w, a1.x, a1.y, a1.z, a1.w};
            float bf[4] = {b4.x, b4.y, b4.z, b4.w};
#pragma unroll
            for (int i = 0; i < 8; i++)
#pragma unroll
                for (int j = 0; j < 4; j++) acc[i][j] += a[i] * bf[j];
        }
    }
#pragma unroll
    for (int i = 0; i < 8; i++) {
        int row = m0 + ty * 8 + i, col = n0 + tx * 4;
        float4 v = make_float4(acc[i][0], acc[i][1], acc[i][2], acc[i][3]);
        if (bias) { float4 bb = *reinterpret_cast<const float4*>(bias + col);
                    v.x += bb.x; v.y += bb.y; v.z += bb.z; v.w += bb.w; }
        if (fuse_gelu) {
            v.x = 0.5f * v.x * (1.0f + erff(v.x * 0.70710678118654752f));
            v.y = 0.5f * v.y * (1.0f + erff(v.y * 0.70710678118654752f));
            v.z = 0.5f * v.z * (1.0f + erff(v.z * 0.70710678118654752f));
            v.w = 0.5f * v.w * (1.0f + erff(v.w * 0.70710678118654752f));
        }
        if (resid) { float4 rr = *reinterpret_cast<const float4*>(resid + (size_t)row * Nn + col);
                     v.x += rr.x; v.y += rr.y; v.z += rr.z; v.w += rr.w; }
        *reinterpret_cast<float4*>(C + (size_t)row * Nn + col) = v;
    }
}

// ---------------- GEMM-T: 64x64 tile, 4x4, prefetch, As stride 68 (proven r10) ----------------
__global__ __launch_bounds__(256) void gemm_t(const float* __restrict__ A, const float* __restrict__ W,
                                              const float* __restrict__ bias, const float* __restrict__ resid,
                                              float* __restrict__ C, int M, int Nn, int K, int fuse_gelu) {
    __shared__ float As[16][68];
    __shared__ float Bs[16][64];
    int t = threadIdx.x, tx = t & 15, ty = t >> 4;
    int m0 = blockIdx.y * 64, n0 = blockIdx.x * 64;
    int mr = t >> 2, kq = (t & 3) * 4;
    int kkb = t >> 4, nq = (t & 15) * 4;
    float4 pa, pb;
    pa = *reinterpret_cast<const float4*>(A + (size_t)(m0 + mr) * K + kq);
    pb = *reinterpret_cast<const float4*>(W + (size_t)kkb * Nn + n0 + nq);
    float acc[4][4] = {};
    for (int k0 = 0; k0 < K; k0 += 16) {
        __syncthreads();
        As[kq][mr] = pa.x; As[kq + 1][mr] = pa.y; As[kq + 2][mr] = pa.z; As[kq + 3][mr] = pa.w;
        *reinterpret_cast<float4*>(&Bs[kkb][nq]) = pb;
        __syncthreads();
        int k1 = k0 + 16;
        if (k1 < K) {
            pa = *reinterpret_cast<const float4*>(A + (size_t)(m0 + mr) * K + k1 + kq);
            pb = *reinterpret_cast<const float4*>(W + (size_t)(k1 + kkb) * Nn + n0 + nq);
        }
#pragma unroll
        for (int kk = 0; kk < 16; kk++) {
            float4 a4 = *reinterpret_cast<float4*>(&As[kk][ty * 4]);
            float4 b4 = *reinterpret_cast<float4*>(&Bs[kk][tx * 4]);
            float a[4] = {a4.x, a4.y, a4.z, a4.w};
            float bf[4] = {b4.x, b4.y, b4.z, b4.w};
#pragma unroll
            for (int i = 0; i < 4; i++)
#pragma unroll
                for (int j = 0; j < 4; j++) acc[i][j] += a[i] * bf[j];
        }
    }
#pragma unroll
    for (int i = 0; i < 4; i++) {
#pragma unroll
        for (int j = 0; j < 4; j++) {
            int row = m0 + ty * 4 + i, col = n0 + tx * 4 + j;
            float v = acc[i][j];
            if (bias) v += bias[col];
            if (fuse_gelu) v = 0.5f * v * (1.0f + erff(v * 0.70710678118654752f));
            if (resid) v += resid[(size_t)row * Nn + col];
            C[(size_t)row * Nn + col] = v;
        }
    }
}

// ---------------- Attention v5: flash-style, 64-row Q-tile per block, GEMM-style S/PV ----------------
// S-gemm keeps the d-ascending dot chain (scores bit-identical to attn2b); online softmax
// adds ~1e-6 reassociation. Ps rows are wave-partitioned -> no barrier for P write->read.
__global__ __launch_bounds__(256) void attn5(const float* __restrict__ q, const float* __restrict__ kv,
                                             float* __restrict__ o) {
    int bh = blockIdx.x, b = bh >> 3, h = bh & 7;
    int qt = blockIdx.y;
    int t = threadIdx.x, tx = t & 15, ty = t >> 4;   // rows ty*4+i, cols tx*4+j
    __shared__ float Qt[32][68];   // Q^T[d][qr]
    __shared__ float Kt[32][68];   // K^T[d][kc]
    __shared__ float Vs[64][34];   // V[kc][d], stride 34 (b64-aligned, 2-way)
    __shared__ float Ps[64][68];   // P[qr][kc]
    const float scale = 0.17677669529663687f;  // 1/sqrt(32)
    const float* kbase = kv + (size_t)b * 1024 * 512 + h * 32;
    const float* vbase = kbase + 256;

    {   // stage Q transposed (2 rounds of the proven stride-68 transpose pattern)
        int mr = t >> 2, kq4 = (t & 3) * 4;
        const float* qsrc = q + ((size_t)(b * 1024 + qt * 64 + mr)) * DMODEL + h * 32;
#pragma unroll
        for (int r = 0; r < 2; r++) {
            float4 a4 = *reinterpret_cast<const float4*>(qsrc + kq4 + 16 * r);
            Qt[kq4 + 16 * r + 0][mr] = a4.x;
            Qt[kq4 + 16 * r + 1][mr] = a4.y;
            Qt[kq4 + 16 * r + 2][mr] = a4.z;
            Qt[kq4 + 16 * r + 3][mr] = a4.w;
        }
    }
    float m_i[4], l_i[4], acc_o[4][2];
#pragma unroll
    for (int i = 0; i < 4; i++) { m_i[i] = -1e30f; l_i[i] = 0.0f; acc_o[i][0] = 0.0f; acc_o[i][1] = 0.0f; }

    for (int kt = 0; kt < 16; kt++) {
        __syncthreads();   // protect Kt/Vs from prior-iteration readers (also covers Q stage on kt=0)
        {   // stage K transposed
            int kr = t >> 2, kq4 = (t & 3) * 4;
            const float* ksrc = kbase + (size_t)(kt * 64 + kr) * 512;
#pragma unroll
            for (int r = 0; r < 2; r++) {
                float4 a4 = *reinterpret_cast<const float4*>(ksrc + kq4 + 16 * r);
                Kt[kq4 + 16 * r + 0][kr] = a4.x;
                Kt[kq4 + 16 * r + 1][kr] = a4.y;
                Kt[kq4 + 16 * r + 2][kr] = a4.z;
                Kt[kq4 + 16 * r + 3][kr] = a4.w;
            }
        }
        {   // stage V row-major (proven pattern), stride 34 -> 2-way
#pragma unroll
            for (int i = 0; i < 8; i++) {
                int idx = t * 8 + i; int kr = idx >> 5, d = idx & 31;
                Vs[kr][d] = vbase[(size_t)(kt * 64 + kr) * 512 + d];
            }
        }
        __syncthreads();
        // S-gemm: acc_s[i][j] = sum_d Q[row][d]*K[col][d], d ascending (bit-identical chain)
        float acc_s[4][4] = {};
#pragma unroll
        for (int d = 0; d < 32; d++) {
            float4 a4 = *reinterpret_cast<float4*>(&Qt[d][ty * 4]);
            float4 b4 = *reinterpret_cast<float4*>(&Kt[d][tx * 4]);
            float a[4] = {a4.x, a4.y, a4.z, a4.w};
            float bb[4] = {b4.x, b4.y, b4.z, b4.w};
#pragma unroll
            for (int i = 0; i < 4; i++)
#pragma unroll
                for (int j = 0; j < 4; j++) acc_s[i][j] += a[i] * bb[j];
        }
        // online softmax per row (16 tx lanes of a row are consecutive -> shfl width 16)
#pragma unroll
        for (int i = 0; i < 4; i++) {
            float s0 = acc_s[i][0] * scale, s1 = acc_s[i][1] * scale;
            float s2 = acc_s[i][2] * scale, s3 = acc_s[i][3] * scale;
            float ml = fmaxf(fmaxf(s0, s1), fmaxf(s2, s3));
            for (int off = 1; off < 16; off <<= 1) ml = fmaxf(ml, __shfl_xor(ml, off));
            float mnew = fmaxf(m_i[i], ml);
            float alpha = __expf(m_i[i] - mnew);
            m_i[i] = mnew;
            float p0 = __expf(s0 - mnew), p1 = __expf(s1 - mnew);
            float p2 = __expf(s2 - mnew), p3 = __expf(s3 - mnew);
            float rs = p0 + p1 + p2 + p3;
            for (int off = 1; off < 16; off <<= 1) rs += __shfl_xor(rs, off);
            l_i[i] = l_i[i] * alpha + rs;
            acc_o[i][0] *= alpha; acc_o[i][1] *= alpha;
            *reinterpret_cast<float4*>(&Ps[ty * 4 + i][tx * 4]) = make_float4(p0, p1, p2, p3);
        }
        // PV: acc_o[i][dvj] += sum_kc P[row][kc]*V[kc][tx*2+dvj]  (wave-local Ps rows, no barrier)
#pragma unroll
        for (int kc0 = 0; kc0 < 64; kc0 += 4) {
            float2 v0 = *reinterpret_cast<float2*>(&Vs[kc0 + 0][tx * 2]);
            float2 v1 = *reinterpret_cast<float2*>(&Vs[kc0 + 1][tx * 2]);
            float2 v2 = *reinterpret_cast<float2*>(&Vs[kc0 + 2][tx * 2]);
            float2 v3 = *reinterpret_cast<float2*>(&Vs[kc0 + 3][tx * 2]);
#pragma unroll
            for (int i = 0; i < 4; i++) {
                float4 p4 = *reinterpret_cast<float4*>(&Ps[ty * 4 + i][kc0]);
                acc_o[i][0] += p4.x * v0.x; acc_o[i][1] += p4.x * v0.y;
                acc_o[i][0] += p4.y * v1.x; acc_o[i][1] += p4.y * v1.y;
                acc_o[i][0] += p4.z * v2.x; acc_o[i][1] += p4.z * v2.y;
                acc_o[i][0] += p4.w * v3.x; acc_o[i][1] += p4.w * v3.y;
            }
        }
    }
    float* obase = o + ((size_t)(b * 1024 + qt * 64)) * DMODEL + h * 32;
#pragma unroll
    for (int i = 0; i < 4; i++) {
        float invl = 1.0f / l_i[i];
        *reinterpret_cast<float2*>(obase + (size_t)(ty * 4 + i) * DMODEL + tx * 2) =
            make_float2(acc_o[i][0] * invl, acc_o[i][1] * invl);
    }
}

// ---------------- K-means v2 (proven r10) ----------------
__global__ __launch_bounds__(256) void km_zero0(float* __restrict__ sums, float* __restrict__ counts) {
    int i = blockIdx.x * 256 + threadIdx.x;
    if (i < NCLUST * DMODEL) sums[i] = 0.0f;
    if (i < NCLUST) counts[i] = 0.0f;
}

__global__ __launch_bounds__(64) void csq_k(const float* __restrict__ centers, float* __restrict__ csq) {
    int j = blockIdx.x, l = threadIdx.x;
    float4 c4 = *reinterpret_cast<const float4*>(centers + j * DMODEL + l * 4);
    float s = c4.x * c4.x + c4.y * c4.y + c4.z * c4.z + c4.w * c4.w;
    for (int off = 1; off < 64; off <<= 1) s += __shfl_xor(s, off);
    if (l == 0) csq[j] = s;
}

__global__ __launch_bounds__(256) void km_dist(const float* __restrict__ A, const float* __restrict__ Cn,
                                               float* __restrict__ dot) {
    __shared__ float As[16][68];
    __shared__ float Bs[16][64];
    int t = threadIdx.x, tx = t & 15, ty = t >> 4;
    int m0 = blockIdx.x * 64;
    int mr = t >> 2, kq = (t & 3) * 4;
    int jb = t & 63, kb = (t >> 6) * 4;
    float acc[4][4] = {};
    for (int k0 = 0; k0 < 256; k0 += 16) {
        __syncthreads();
        {
            float4 a4 = *reinterpret_cast<const float4*>(A + (size_t)(m0 + mr) * DMODEL + k0 + kq);
            As[kq][mr] = a4.x; As[kq + 1][mr] = a4.y; As[kq + 2][mr] = a4.z; As[kq + 3][mr] = a4.w;
        }
        {
            float4 c4 = *reinterpret_cast<const float4*>(Cn + (size_t)jb * DMODEL + k0 + kb);
            Bs[kb][jb] = c4.x; Bs[kb + 1][jb] = c4.y; Bs[kb + 2][jb] = c4.z; Bs[kb + 3][jb] = c4.w;
        }
        __syncthreads();
#pragma unroll
        for (int kk = 0; kk < 16; kk++) {
            float4 a4 = *reinterpret_cast<float4*>(&As[kk][ty * 4]);
            float4 b4 = *reinterpret_cast<float4*>(&Bs[kk][tx * 4]);
            float a[4] = {a4.x, a4.y, a4.z, a4.w};
            float bf[4] = {b4.x, b4.y, b4.z, b4.w};
#pragma unroll
            for (int i = 0; i < 4; i++)
#pragma unroll
                for (int j = 0; j < 4; j++) acc[i][j] += a[i] * bf[j];
        }
    }
#pragma unroll
    for (int i = 0; i < 4; i++)
#pragma unroll
        for (int j = 0; j < 4; j++)
            dot[(size_t)(m0 + ty * 4 + i) * NCLUST + tx * 4 + j] = acc[i][j];
}

__global__ __launch_bounds__(256) void km_argmin_segsum(const float* __restrict__ dot, const float* __restrict__ csq,
                                                        const float* __restrict__ xf, int* __restrict__ labels,
                                                        float* __restrict__ counts, float* __restrict__ sums,
                                                        int do_seg) {
    __shared__ float lsum[NCLUST][DMODEL];
    __shared__ int lab_s[128];
    int t = threadIdx.x, w = t >> 6, l = t & 63;
    int base = blockIdx.x * 128;
    float cs = csq[l];
    for (int p = 0; p < 32; p++) {
        int i = base + w * 32 + p;
        float val = cs - 2.0f * dot[(size_t)i * NCLUST + l];
        float best = val; int bi = l;
        for (int off = 1; off < 64; off <<= 1) {
            float ov = __shfl_xor(best, off);
            int oi = __shfl_xor(bi, off);
            if (ov < best || (ov == best && oi < bi)) { best = ov; bi = oi; }
        }
        if (l == 0) {
            labels[i] = bi;
            lab_s[w * 32 + p] = bi;
            if (do_seg) atomicAdd(&counts[bi], 1.0f);
        }
    }
    if (!do_seg) return;
    for (int j = 0; j < NCLUST; j++) lsum[j][t] = 0.0f;
    __syncthreads();
    for (int p = 0; p < 128; p++) {
        int lab = lab_s[p];
        lsum[lab][t] += xf[(size_t)(base + p) * DMODEL + t];
    }
    for (int j = 0; j < NCLUST; j++) atomicAdd(&sums[j * DMODEL + t], lsum[j][t]);
}

__global__ __launch_bounds__(256) void km_update_zero(float* __restrict__ centers, float* __restrict__ sums,
                                                      float* __restrict__ counts, float* __restrict__ csq) {
    __shared__ float red[256];
    int j = blockIdx.x, d = threadIdx.x;
    float c = counts[j];
    float cv = centers[j * DMODEL + d];
    if (c > 0.0f) cv = sums[j * DMODEL + d] / fmaxf(c, 1.0f);
    centers[j * DMODEL + d] = cv;
    red[d] = cv * cv;
    __syncthreads();
    for (int off = 128; off; off >>= 1) { if (d < off) red[d] += red[d + off]; __syncthreads(); }
    if (d == 0) { csq[j] = red[0]; counts[j] = 0.0f; }
    sums[j * DMODEL + d] = 0.0f;
}

__global__ __launch_bounds__(256) void nproj(const float* __restrict__ centers, const float* __restrict__ kW,
                                             const float* __restrict__ kb2, float* __restrict__ outc) {
    int idx = blockIdx.x * 256 + threadIdx.x;
    if (idx >= NCLUST * DMODEL) return;
    int row = idx >> 8, col = idx & 255;
    const float* cr = centers + row * DMODEL;
    float acc = 0.0f;
    for (int d = 0; d < DMODEL; d++) acc += cr[d] * kW[(size_t)d * DMODEL + col];
    outc[idx] = acc + kb2[col];
}

__global__ __launch_bounds__(256) void km_gather(const int* __restrict__ labels, const float* __restrict__ outc,
                                                 float* __restrict__ out) {
    int i = blockIdx.x, t = threadIdx.x;
    int lab = labels[i];
    out[(size_t)i * DMODEL + t] = outc[lab * DMODEL + t];
}

extern "C" void kernel_launch(void* const* d_in, const int* in_sizes, int n_in,
                              void* d_out, int out_size, void* d_ws, size_t ws_size,
                              hipStream_t stream) {
    const float* x_in  = (const float*)d_in[0];
    const float* ln1_g = (const float*)d_in[1];
    const float* ln1_b = (const float*)d_in[2];
    const float* Wq    = (const float*)d_in[3];
    const float* Wkv   = (const float*)d_in[4];
    const float* Wo    = (const float*)d_in[5];
    const float* bo    = (const float*)d_in[6];
    const float* ln2_g = (const float*)d_in[7];
    const float* ln2_b = (const float*)d_in[8];
    const float* W1    = (const float*)d_in[9];
    const float* b1    = (const float*)d_in[10];
    const float* W2    = (const float*)d_in[11];
    const float* b2    = (const float*)d_in[12];
    const float* kWp   = (const float*)d_in[13];
    const float* kbp   = (const float*)d_in[14];
    float* out = (float*)d_out;

    const size_t NEEDED = 42173440;
    if (ws_size < NEEDED) {
        hipMemsetAsync(d_out, 0, (size_t)out_size * sizeof(float), stream);
        return;
    }

    char* ws = (char*)d_ws;
    float* xf      = (float*)(ws);              //  8 MB   residual stream (mutable)
    float* xn      = (float*)(ws + 8388608);    //  8 MB   LN output; aliased as attention output
    float* ao      = xn;
    float* qb      = (float*)(ws + 16777216);   //  8 MB
    float* kvb     = (float*)(ws + 25165824);   // 16 MB
    float* hb      = (float*)(ws + 16777216);   // 16 MB   FFN hidden (qb/kvb dead by then)
    float* dotb    = qb;                        //  2 MB   kmeans dot matrix (qb dead)
    float* centers = (float*)(ws + 41943040);   // 64 KB
    float* sums    = (float*)(ws + 42008576);   // 64 KB
    float* counts  = (float*)(ws + 42074112);   // 256 B
    float* csqb    = (float*)(ws + 42074368);   // 256 B
    int*   labels  = (int*)  (ws + 42075136);   // 32 KB
    float* outc    = (float*)(ws + 42107904);   // 64 KB -> end 42173440

    hipMemcpyAsync(xf, x_in, (size_t)BN * DMODEL * sizeof(float), hipMemcpyDeviceToDevice, stream);

    for (int l = 0; l < 4; l++) {
        ln_wave<<<BN / 4, 256, 0, stream>>>(xf, ln1_g + l * 256, ln1_b + l * 256, xn);
        gemm_b<<<dim3(4, 64), 256, 0, stream>>>(xn, Wq + (size_t)l * 65536, nullptr, nullptr, qb, BN, 256, 256, 0);
        gemm_b<<<dim3(8, 64), 256, 0, stream>>>(xn, Wkv + (size_t)l * 131072, nullptr, nullptr, kvb, BN, 512, 256, 0);
        attn5<<<dim3(64, 16), 256, 0, stream>>>(qb, kvb, ao);   // ao == xn (xn dead now)
        gemm_b<<<dim3(4, 64), 256, 0, stream>>>(ao, Wo + (size_t)l * 65536, bo + l * 256, xf, xf, BN, 256, 256, 0);
        ln_wave<<<BN / 4, 256, 0, stream>>>(xf, ln2_g + l * 256, ln2_b + l * 256, xn);
        // FFN chunked over rows (2 x 4096) so hidden buffer fits in 16 MB (qb/kvb dead)
        for (int c = 0; c < 2; c++) {
            float* xnc = xn + (size_t)c * 4096 * 256;
            float* xfc = xf + (size_t)c * 4096 * 256;
            gemm_b<<<dim3(16, 32), 256, 0, stream>>>(xnc, W1 + (size_t)l * 262144, b1 + l * 1024, nullptr, hb, 4096, 1024, 256, 1);
            gemm_t<<<dim3(4, 64), 256, 0, stream>>>(hb, W2 + (size_t)l * 262144, b2 + l * 256, xfc, xfc, 4096, 256, 1024, 0);
        }
    }

    hipMemcpyAsync(centers, xf, NCLUST * DMODEL * sizeof(float), hipMemcpyDeviceToDevice, stream);
    km_zero0<<<64, 256, 0, stream>>>(sums, counts);
    csq_k<<<64, 64, 0, stream>>>(centers, csqb);
    for (int it = 0; it < 10; it++) {
        km_dist<<<128, 256, 0, stream>>>(xf, centers, dotb);
        km_argmin_segsum<<<64, 256, 0, stream>>>(dotb, csqb, xf, labels, counts, sums, 1);
        km_update_zero<<<64, 256, 0, stream>>>(centers, sums, counts, csqb);
    }
    km_dist<<<128, 256, 0, stream>>>(xf, centers, dotb);
    km_argmin_segsum<<<64, 256, 0, stream>>>(dotb, csqb, xf, labels, counts, sums, 0);
    nproj<<<64, 256, 0, stream>>>(centers, kWp, kbp, outc);
    km_gather<<<BN, 256, 0, stream>>>(labels, outc, out);
}

// Round 12
// 2447.769 us; speedup vs baseline: 1.7991x; 1.1806x over previous
//
#include <hip/hip_runtime.h>
#include <hip/hip_bf16.h>
#include <math.h>

// Problem constants (B=8, N=1024, D=256, L=4, M=1024, H=8, dh=32, K=64 clusters)
#define BN 8192           // B*N rows
#define DMODEL 256
#define FFN 1024
#define NCLUST 64

typedef unsigned short u16;
typedef __attribute__((ext_vector_type(8))) short s16x8;      // 8 bf16 (4 VGPRs) MFMA frag
typedef __attribute__((ext_vector_type(8))) unsigned short u16x8;
typedef __attribute__((ext_vector_type(4))) float f32x4;

__device__ __forceinline__ float bf2f(u16 v) {
    union { unsigned int u; float f; } w; w.u = ((unsigned int)v) << 16; return w.f;
}
__device__ __forceinline__ u16 f2bf(float f) {
    union { float f; unsigned int u; } w; w.f = f;
    unsigned int r = w.u + 0x7fffu + ((w.u >> 16) & 1u);
    return (u16)(r >> 16);
}

// ---------------- LayerNorm: one wave per row, float4 + shuffle reduce (proven r7) ----------------
__global__ __launch_bounds__(256) void ln_wave(const float* __restrict__ x, const float* __restrict__ g,
                                               const float* __restrict__ b, float* __restrict__ y) {
    int t = threadIdx.x, w = t >> 6, l = t & 63;
    int row = blockIdx.x * 4 + w;
    const float* xr = x + (size_t)row * DMODEL;
    float4 v = *reinterpret_cast<const float4*>(xr + l * 4);
    float s = v.x + v.y + v.z + v.w;
    for (int off = 1; off < 64; off <<= 1) s += __shfl_xor(s, off);
    float mean = s * (1.0f / 256.0f);
    float4 dv = make_float4(v.x - mean, v.y - mean, v.z - mean, v.w - mean);
    float vs = dv.x * dv.x + dv.y * dv.y + dv.z * dv.z + dv.w * dv.w;
    for (int off = 1; off < 64; off <<= 1) vs += __shfl_xor(vs, off);
    float rs = rsqrtf(vs * (1.0f / 256.0f) + 1e-5f);
    float4 gg = *reinterpret_cast<const float4*>(g + l * 4);
    float4 bb = *reinterpret_cast<const float4*>(b + l * 4);
    float4 out = make_float4(dv.x * rs * gg.x + bb.x, dv.y * rs * gg.y + bb.y,
                             dv.z * rs * gg.z + bb.z, dv.w * rs * gg.w + bb.w);
    *reinterpret_cast<float4*>(y + (size_t)row * DMODEL + l * 4) = out;
}

// ---------------- Weight convert: W[K][N] fp32 -> Wt_hi[n][k], Wt_lo[n][k] bf16 ----------------
__global__ __launch_bounds__(256) void wconv(const float* __restrict__ W, u16* __restrict__ th,
                                             u16* __restrict__ tl, int K, int N) {
    int idx = blockIdx.x * 256 + threadIdx.x;   // idx = n*K + k  (output-coalesced)
    int n = idx / K, k = idx - n * K;
    float x = W[(size_t)k * N + n];
    u16 h = f2bf(x);
    th[idx] = h;
    tl[idx] = f2bf(x - bf2f(h));
}

// ---------------- MFMA GEMM (bf16x2): C = A(f32) @ W + epilogue ----------------
// A hi/lo split in staging; W pre-split/transposed (Bt[n][k] bf16). 128x64 tile, BK=32.
// Wave w: rows [w*32, w*32+32) as 2 m-frags x 4 n-frags; 24 MFMAs per wave per BK.
// Error ~2^-17 relative (AlBl dropped) -- inside the empirically label-safe band.
__global__ __launch_bounds__(256) void gemm_mx(const float* __restrict__ A, const u16* __restrict__ Bth,
                                               const u16* __restrict__ Btl, const float* __restrict__ bias,
                                               const float* __restrict__ resid, float* __restrict__ C,
                                               int M, int N, int K, int fuse_gelu) {
    __shared__ u16 Ah[128][56], Al[128][56];   // stride 56 bf16 = 112 B: 16B-aligned, 2-way banks
    __shared__ u16 Bh[64][56],  Bl[64][56];
    int t = threadIdx.x;
    int m0 = blockIdx.y * 128, n0 = blockIdx.x * 64;
    int L = t & 63, w = t >> 6, fr = L & 15, quad = L >> 4;
    int sm = t >> 1, skh = (t & 1) * 16;       // A staging: thread -> row sm, 16 k's
    int sn = t >> 2, skq = (t & 3) * 8;        // B staging: thread -> row sn, 8 k's
    f32x4 acc[2][4];
#pragma unroll
    for (int i = 0; i < 2; i++)
#pragma unroll
        for (int j = 0; j < 4; j++) acc[i][j] = (f32x4){0.0f, 0.0f, 0.0f, 0.0f};

    for (int k0 = 0; k0 < K; k0 += 32) {
        __syncthreads();
        {   // stage A: fp32 -> hi/lo bf16
            const float* asrc = A + (size_t)(m0 + sm) * K + k0 + skh;
            float4 x0 = *reinterpret_cast<const float4*>(asrc);
            float4 x1 = *reinterpret_cast<const float4*>(asrc + 4);
            float4 x2 = *reinterpret_cast<const float4*>(asrc + 8);
            float4 x3 = *reinterpret_cast<const float4*>(asrc + 12);
            float xs[16] = {x0.x, x0.y, x0.z, x0.w, x1.x, x1.y, x1.z, x1.w,
                            x2.x, x2.y, x2.z, x2.w, x3.x, x3.y, x3.z, x3.w};
            u16x8 h0, h1, l0, l1;
#pragma unroll
            for (int j = 0; j < 8; j++) {
                u16 ha = f2bf(xs[j]);     h0[j] = ha; l0[j] = f2bf(xs[j] - bf2f(ha));
                u16 hb = f2bf(xs[j + 8]); h1[j] = hb; l1[j] = f2bf(xs[j + 8] - bf2f(hb));
            }
            *reinterpret_cast<u16x8*>(&Ah[sm][skh])     = h0;
            *reinterpret_cast<u16x8*>(&Ah[sm][skh + 8]) = h1;
            *reinterpret_cast<u16x8*>(&Al[sm][skh])     = l0;
            *reinterpret_cast<u16x8*>(&Al[sm][skh + 8]) = l1;
        }
        {   // stage B: pre-split bf16, coalesced 16B loads
            size_t go = (size_t)(n0 + sn) * K + k0 + skq;
            *reinterpret_cast<u16x8*>(&Bh[sn][skq]) = *reinterpret_cast<const u16x8*>(Bth + go);
            *reinterpret_cast<u16x8*>(&Bl[sn][skq]) = *reinterpret_cast<const u16x8*>(Btl + go);
        }
        __syncthreads();
        s16x8 ah[2], al[2];
#pragma unroll
        for (int mi = 0; mi < 2; mi++) {
            int row = w * 32 + mi * 16 + fr;
            ah[mi] = *reinterpret_cast<s16x8*>(&Ah[row][quad * 8]);
            al[mi] = *reinterpret_cast<s16x8*>(&Al[row][quad * 8]);
        }
#pragma unroll
        for (int ni = 0; ni < 4; ni++) {
            int rn = ni * 16 + fr;
            s16x8 bhf = *reinterpret_cast<s16x8*>(&Bh[rn][quad * 8]);
            s16x8 blf = *reinterpret_cast<s16x8*>(&Bl[rn][quad * 8]);
#pragma unroll
            for (int mi = 0; mi < 2; mi++) {
                acc[mi][ni] = __builtin_amdgcn_mfma_f32_16x16x32_bf16(ah[mi], bhf, acc[mi][ni], 0, 0, 0);
                acc[mi][ni] = __builtin_amdgcn_mfma_f32_16x16x32_bf16(ah[mi], blf, acc[mi][ni], 0, 0, 0);
                acc[mi][ni] = __builtin_amdgcn_mfma_f32_16x16x32_bf16(al[mi], bhf, acc[mi][ni], 0, 0, 0);
            }
        }
    }
    // writeback: D col = lane&15, row = quad*4 + reg  (m89-verified layout)
#pragma unroll
    for (int mi = 0; mi < 2; mi++) {
#pragma unroll
        for (int ni = 0; ni < 4; ni++) {
#pragma unroll
            for (int r = 0; r < 4; r++) {
                int row = m0 + w * 32 + mi * 16 + quad * 4 + r;
                int col = n0 + ni * 16 + fr;
                float v = acc[mi][ni][r];
                if (bias) v += bias[col];
                if (fuse_gelu) v = 0.5f * v * (1.0f + erff(v * 0.70710678118654752f));
                if (resid) v += resid[(size_t)row * N + col];
                C[(size_t)row * N + col] = v;
            }
        }
    }
}

// ---------------- Attention v5 (r11) + Vs stride 36 (kills the 4-way staging conflict) ----------------
__global__ __launch_bounds__(256) void attn5(const float* __restrict__ q, const float* __restrict__ kv,
                                             float* __restrict__ o) {
    int bh = blockIdx.x, b = bh >> 3, h = bh & 7;
    int qt = blockIdx.y;
    int t = threadIdx.x, tx = t & 15, ty = t >> 4;
    __shared__ float Qt[32][68];
    __shared__ float Kt[32][68];
    __shared__ float Vs[64][36];   // stride 36: staging banks 2-way, float2 reads 8B-aligned
    __shared__ float Ps[64][68];
    const float scale = 0.17677669529663687f;  // 1/sqrt(32)
    const float* kbase = kv + (size_t)b * 1024 * 512 + h * 32;
    const float* vbase = kbase + 256;

    {
        int mr = t >> 2, kq4 = (t & 3) * 4;
        const float* qsrc = q + ((size_t)(b * 1024 + qt * 64 + mr)) * DMODEL + h * 32;
#pragma unroll
        for (int r = 0; r < 2; r++) {
            float4 a4 = *reinterpret_cast<const float4*>(qsrc + kq4 + 16 * r);
            Qt[kq4 + 16 * r + 0][mr] = a4.x;
            Qt[kq4 + 16 * r + 1][mr] = a4.y;
            Qt[kq4 + 16 * r + 2][mr] = a4.z;
            Qt[kq4 + 16 * r + 3][mr] = a4.w;
        }
    }
    float m_i[4], l_i[4], acc_o[4][2];
#pragma unroll
    for (int i = 0; i < 4; i++) { m_i[i] = -1e30f; l_i[i] = 0.0f; acc_o[i][0] = 0.0f; acc_o[i][1] = 0.0f; }

    for (int kt = 0; kt < 16; kt++) {
        __syncthreads();
        {
            int kr = t >> 2, kq4 = (t & 3) * 4;
            const float* ksrc = kbase + (size_t)(kt * 64 + kr) * 512;
#pragma unroll
            for (int r = 0; r < 2; r++) {
                float4 a4 = *reinterpret_cast<const float4*>(ksrc + kq4 + 16 * r);
                Kt[kq4 + 16 * r + 0][kr] = a4.x;
                Kt[kq4 + 16 * r + 1][kr] = a4.y;
                Kt[kq4 + 16 * r + 2][kr] = a4.z;
                Kt[kq4 + 16 * r + 3][kr] = a4.w;
            }
        }
        {
#pragma unroll
            for (int i = 0; i < 8; i++) {
                int idx = t * 8 + i; int kr = idx >> 5, d = idx & 31;
                Vs[kr][d] = vbase[(size_t)(kt * 64 + kr) * 512 + d];
            }
        }
        __syncthreads();
        float acc_s[4][4] = {};
#pragma unroll
        for (int d = 0; d < 32; d++) {
            float4 a4 = *reinterpret_cast<float4*>(&Qt[d][ty * 4]);
            float4 b4 = *reinterpret_cast<float4*>(&Kt[d][tx * 4]);
            float a[4] = {a4.x, a4.y, a4.z, a4.w};
            float bb[4] = {b4.x, b4.y, b4.z, b4.w};
#pragma unroll
            for (int i = 0; i < 4; i++)
#pragma unroll
                for (int j = 0; j < 4; j++) acc_s[i][j] += a[i] * bb[j];
        }
#pragma unroll
        for (int i = 0; i < 4; i++) {
            float s0 = acc_s[i][0] * scale, s1 = acc_s[i][1] * scale;
            float s2 = acc_s[i][2] * scale, s3 = acc_s[i][3] * scale;
            float ml = fmaxf(fmaxf(s0, s1), fmaxf(s2, s3));
            for (int off = 1; off < 16; off <<= 1) ml = fmaxf(ml, __shfl_xor(ml, off));
            float mnew = fmaxf(m_i[i], ml);
            float alpha = __expf(m_i[i] - mnew);
            m_i[i] = mnew;
            float p0 = __expf(s0 - mnew), p1 = __expf(s1 - mnew);
            float p2 = __expf(s2 - mnew), p3 = __expf(s3 - mnew);
            float rs = p0 + p1 + p2 + p3;
            for (int off = 1; off < 16; off <<= 1) rs += __shfl_xor(rs, off);
            l_i[i] = l_i[i] * alpha + rs;
            acc_o[i][0] *= alpha; acc_o[i][1] *= alpha;
            *reinterpret_cast<float4*>(&Ps[ty * 4 + i][tx * 4]) = make_float4(p0, p1, p2, p3);
        }
#pragma unroll
        for (int kc0 = 0; kc0 < 64; kc0 += 4) {
            float2 v0 = *reinterpret_cast<float2*>(&Vs[kc0 + 0][tx * 2]);
            float2 v1 = *reinterpret_cast<float2*>(&Vs[kc0 + 1][tx * 2]);
            float2 v2 = *reinterpret_cast<float2*>(&Vs[kc0 + 2][tx * 2]);
            float2 v3 = *reinterpret_cast<float2*>(&Vs[kc0 + 3][tx * 2]);
#pragma unroll
            for (int i = 0; i < 4; i++) {
                float4 p4 = *reinterpret_cast<float4*>(&Ps[ty * 4 + i][kc0]);
                acc_o[i][0] += p4.x * v0.x; acc_o[i][1] += p4.x * v0.y;
                acc_o[i][0] += p4.y * v1.x; acc_o[i][1] += p4.y * v1.y;
                acc_o[i][0] += p4.z * v2.x; acc_o[i][1] += p4.z * v2.y;
                acc_o[i][0] += p4.w * v3.x; acc_o[i][1] += p4.w * v3.y;
            }
        }
    }
    float* obase = o + ((size_t)(b * 1024 + qt * 64)) * DMODEL + h * 32;
#pragma unroll
    for (int i = 0; i < 4; i++) {
        float invl = 1.0f / l_i[i];
        *reinterpret_cast<float2*>(obase + (size_t)(ty * 4 + i) * DMODEL + tx * 2) =
            make_float2(acc_o[i][0] * invl, acc_o[i][1] * invl);
    }
}

// ---------------- K-means v2 (proven r10/r11) ----------------
__global__ __launch_bounds__(256) void km_zero0(float* __restrict__ sums, float* __restrict__ counts) {
    int i = blockIdx.x * 256 + threadIdx.x;
    if (i < NCLUST * DMODEL) sums[i] = 0.0f;
    if (i < NCLUST) counts[i] = 0.0f;
}

__global__ __launch_bounds__(64) void csq_k(const float* __restrict__ centers, float* __restrict__ csq) {
    int j = blockIdx.x, l = threadIdx.x;
    float4 c4 = *reinterpret_cast<const float4*>(centers + j * DMODEL + l * 4);
    float s = c4.x * c4.x + c4.y * c4.y + c4.z * c4.z + c4.w * c4.w;
    for (int off = 1; off < 64; off <<= 1) s += __shfl_xor(s, off);
    if (l == 0) csq[j] = s;
}

__global__ __launch_bounds__(256) void km_dist(const float* __restrict__ A, const float* __restrict__ Cn,
                                               float* __restrict__ dot) {
    __shared__ float As[16][68];
    __shared__ float Bs[16][64];
    int t = threadIdx.x, tx = t & 15, ty = t >> 4;
    int m0 = blockIdx.x * 64;
    int mr = t >> 2, kq = (t & 3) * 4;
    int jb = t & 63, kb = (t >> 6) * 4;
    float acc[4][4] = {};
    for (int k0 = 0; k0 < 256; k0 += 16) {
        __syncthreads();
        {
            float4 a4 = *reinterpret_cast<const float4*>(A + (size_t)(m0 + mr) * DMODEL + k0 + kq);
            As[kq][mr] = a4.x; As[kq + 1][mr] = a4.y; As[kq + 2][mr] = a4.z; As[kq + 3][mr] = a4.w;
        }
        {
            float4 c4 = *reinterpret_cast<const float4*>(Cn + (size_t)jb * DMODEL + k0 + kb);
            Bs[kb][jb] = c4.x; Bs[kb + 1][jb] = c4.y; Bs[kb + 2][jb] = c4.z; Bs[kb + 3][jb] = c4.w;
        }
        __syncthreads();
#pragma unroll
        for (int kk = 0; kk < 16; kk++) {
            float4 a4 = *reinterpret_cast<float4*>(&As[kk][ty * 4]);
            float4 b4 = *reinterpret_cast<float4*>(&Bs[kk][tx * 4]);
            float a[4] = {a4.x, a4.y, a4.z, a4.w};
            float bf[4] = {b4.x, b4.y, b4.z, b4.w};
#pragma unroll
            for (int i = 0; i < 4; i++)
#pragma unroll
                for (int j = 0; j < 4; j++) acc[i][j] += a[i] * bf[j];
        }
    }
#pragma unroll
    for (int i = 0; i < 4; i++)
#pragma unroll
        for (int j = 0; j < 4; j++)
            dot[(size_t)(m0 + ty * 4 + i) * NCLUST + tx * 4 + j] = acc[i][j];
}

__global__ __launch_bounds__(256) void km_argmin_segsum(const float* __restrict__ dot, const float* __restrict__ csq,
                                                        const float* __restrict__ xf, int* __restrict__ labels,
                                                        float* __restrict__ counts, float* __restrict__ sums,
                                                        int do_seg) {
    __shared__ float lsum[NCLUST][DMODEL];
    __shared__ int lab_s[128];
    int t = threadIdx.x, w = t >> 6, l = t & 63;
    int base = blockIdx.x * 128;
    float cs = csq[l];
    for (int p = 0; p < 32; p++) {
        int i = base + w * 32 + p;
        float val = cs - 2.0f * dot[(size_t)i * NCLUST + l];
        float best = val; int bi = l;
        for (int off = 1; off < 64; off <<= 1) {
            float ov = __shfl_xor(best, off);
            int oi = __shfl_xor(bi, off);
            if (ov < best || (ov == best && oi < bi)) { best = ov; bi = oi; }
        }
        if (l == 0) {
            labels[i] = bi;
            lab_s[w * 32 + p] = bi;
            if (do_seg) atomicAdd(&counts[bi], 1.0f);
        }
    }
    if (!do_seg) return;
    for (int j = 0; j < NCLUST; j++) lsum[j][t] = 0.0f;
    __syncthreads();
    for (int p = 0; p < 128; p++) {
        int lab = lab_s[p];
        lsum[lab][t] += xf[(size_t)(base + p) * DMODEL + t];
    }
    for (int j = 0; j < NCLUST; j++) atomicAdd(&sums[j * DMODEL + t], lsum[j][t]);
}

__global__ __launch_bounds__(256) void km_update_zero(float* __restrict__ centers, float* __restrict__ sums,
                                                      float* __restrict__ counts, float* __restrict__ csq) {
    __shared__ float red[256];
    int j = blockIdx.x, d = threadIdx.x;
    float c = counts[j];
    float cv = centers[j * DMODEL + d];
    if (c > 0.0f) cv = sums[j * DMODEL + d] / fmaxf(c, 1.0f);
    centers[j * DMODEL + d] = cv;
    red[d] = cv * cv;
    __syncthreads();
    for (int off = 128; off; off >>= 1) { if (d < off) red[d] += red[d + off]; __syncthreads(); }
    if (d == 0) { csq[j] = red[0]; counts[j] = 0.0f; }
    sums[j * DMODEL + d] = 0.0f;
}

__global__ __launch_bounds__(256) void nproj(const float* __restrict__ centers, const float* __restrict__ kW,
                                             const float* __restrict__ kb2, float* __restrict__ outc) {
    int idx = blockIdx.x * 256 + threadIdx.x;
    if (idx >= NCLUST * DMODEL) return;
    int row = idx >> 8, col = idx & 255;
    const float* cr = centers + row * DMODEL;
    float acc = 0.0f;
    for (int d = 0; d < DMODEL; d++) acc += cr[d] * kW[(size_t)d * DMODEL + col];
    outc[idx] = acc + kb2[col];
}

__global__ __launch_bounds__(256) void km_gather(const int* __restrict__ labels, const float* __restrict__ outc,
                                                 float* __restrict__ out) {
    int i = blockIdx.x, t = threadIdx.x;
    int lab = labels[i];
    out[(size_t)i * DMODEL + t] = outc[lab * DMODEL + t];
}

extern "C" void kernel_launch(void* const* d_in, const int* in_sizes, int n_in,
                              void* d_out, int out_size, void* d_ws, size_t ws_size,
                              hipStream_t stream) {
    const float* x_in  = (const float*)d_in[0];
    const float* ln1_g = (const float*)d_in[1];
    const float* ln1_b = (const float*)d_in[2];
    const float* Wq    = (const float*)d_in[3];
    const float* Wkv   = (const float*)d_in[4];
    const float* Wo    = (const float*)d_in[5];
    const float* bo    = (const float*)d_in[6];
    const float* ln2_g = (const float*)d_in[7];
    const float* ln2_b = (const float*)d_in[8];
    const float* W1    = (const float*)d_in[9];
    const float* b1    = (const float*)d_in[10];
    const float* W2    = (const float*)d_in[11];
    const float* b2    = (const float*)d_in[12];
    const float* kWp   = (const float*)d_in[13];
    const float* kbp   = (const float*)d_in[14];
    float* out = (float*)d_out;

    // Layout (bytes): xf 0-8M | xn 8-16M | qb 16-24M | kvb 24-40M | hb 16-48M (FFN, q/kv dead)
    //                 kmeans 41.94-42.17M (inside hb span, temporally disjoint) | wsplit 48-51.1M
    const size_t NEEDED = 53477376;
    if (ws_size < NEEDED) {
        hipMemsetAsync(d_out, 0, (size_t)out_size * sizeof(float), stream);
        return;   // signature: absmax ~0.707 => workspace too small
    }

    char* ws = (char*)d_ws;
    float* xf      = (float*)(ws);
    float* xn      = (float*)(ws + 8388608);
    float* ao      = xn;
    float* qb      = (float*)(ws + 16777216);
    float* kvb     = (float*)(ws + 25165824);
    float* hb      = (float*)(ws + 16777216);   // 32 MB span 16-48 MB during FFN
    float* dotb    = qb;
    float* centers = (float*)(ws + 41943040);
    float* sums    = (float*)(ws + 42008576);
    float* counts  = (float*)(ws + 42074112);
    float* csqb    = (float*)(ws + 42074368);
    int*   labels  = (int*)  (ws + 42075136);
    float* outc    = (float*)(ws + 42107904);
    u16*   wr      = (u16*)  (ws + 50331648);   // per-layer split weights (3.1 MB)
    u16 *wqh = wr,            *wql = wr + 65536;
    u16 *wkvh = wr + 131072,  *wkvl = wr + 262144;
    u16 *woh = wr + 393216,   *wol = wr + 458752;
    u16 *w1h = wr + 524288,   *w1l = wr + 786432;
    u16 *w2h = wr + 1048576,  *w2l = wr + 1310720;

    hipMemcpyAsync(xf, x_in, (size_t)BN * DMODEL * sizeof(float), hipMemcpyDeviceToDevice, stream);

    for (int l = 0; l < 4; l++) {
        wconv<<<256, 256, 0, stream>>>(Wq + (size_t)l * 65536, wqh, wql, 256, 256);
        wconv<<<512, 256, 0, stream>>>(Wkv + (size_t)l * 131072, wkvh, wkvl, 256, 512);
        wconv<<<256, 256, 0, stream>>>(Wo + (size_t)l * 65536, woh, wol, 256, 256);
        wconv<<<1024, 256, 0, stream>>>(W1 + (size_t)l * 262144, w1h, w1l, 256, 1024);
        wconv<<<1024, 256, 0, stream>>>(W2 + (size_t)l * 262144, w2h, w2l, 1024, 256);

        ln_wave<<<BN / 4, 256, 0, stream>>>(xf, ln1_g + l * 256, ln1_b + l * 256, xn);
        gemm_mx<<<dim3(4, 64), 256, 0, stream>>>(xn, wqh, wql, nullptr, nullptr, qb, BN, 256, 256, 0);
        gemm_mx<<<dim3(8, 64), 256, 0, stream>>>(xn, wkvh, wkvl, nullptr, nullptr, kvb, BN, 512, 256, 0);
        attn5<<<dim3(64, 16), 256, 0, stream>>>(qb, kvb, ao);
        gemm_mx<<<dim3(4, 64), 256, 0, stream>>>(ao, woh, wol, bo + l * 256, xf, xf, BN, 256, 256, 0);
        ln_wave<<<BN / 4, 256, 0, stream>>>(xf, ln2_g + l * 256, ln2_b + l * 256, xn);
        gemm_mx<<<dim3(16, 64), 256, 0, stream>>>(xn, w1h, w1l, b1 + l * 1024, nullptr, hb, BN, 1024, 256, 1);
        gemm_mx<<<dim3(4, 64), 256, 0, stream>>>(hb, w2h, w2l, b2 + l * 256, xf, xf, BN, 256, 1024, 0);
    }

    hipMemcpyAsync(centers, xf, NCLUST * DMODEL * sizeof(float), hipMemcpyDeviceToDevice, stream);
    km_zero0<<<64, 256, 0, stream>>>(sums, counts);
    csq_k<<<64, 64, 0, stream>>>(centers, csqb);
    for (int it = 0; it < 10; it++) {
        km_dist<<<128, 256, 0, stream>>>(xf, centers, dotb);
        km_argmin_segsum<<<64, 256, 0, stream>>>(dotb, csqb, xf, labels, counts, sums, 1);
        km_update_zero<<<64, 256, 0, stream>>>(centers, sums, counts, csqb);
    }
    km_dist<<<128, 256, 0, stream>>>(xf, centers, dotb);
    km_argmin_segsum<<<64, 256, 0, stream>>>(dotb, csqb, xf, labels, counts, sums, 0);
    nproj<<<64, 256, 0, stream>>>(centers, kWp, kbp, outc);
    km_gather<<<BN, 256, 0, stream>>>(labels, outc, out);
}

// Round 13
// 1940.567 us; speedup vs baseline: 2.2693x; 1.2614x over previous
//
#include <hip/hip_runtime.h>
#include <hip/hip_bf16.h>
#include <math.h>

// Problem constants (B=8, N=1024, D=256, L=4, M=1024, H=8, dh=32, K=64 clusters)
#define BN 8192           // B*N rows
#define DMODEL 256
#define FFN 1024
#define NCLUST 64

typedef unsigned short u16;
typedef unsigned int u32;
typedef __attribute__((ext_vector_type(8))) short s16x8;      // 8 bf16 (4 VGPRs) MFMA frag
typedef __attribute__((ext_vector_type(8))) unsigned short u16x8;
typedef __attribute__((ext_vector_type(4))) unsigned short u16x4;
typedef __attribute__((ext_vector_type(4))) float f32x4;

__device__ __forceinline__ float bf2f(u16 v) {
    union { unsigned int u; float f; } w; w.u = ((unsigned int)v) << 16; return w.f;
}
__device__ __forceinline__ u16 f2bf(float f) {
    union { float f; unsigned int u; } w; w.f = f;
    unsigned int r = w.u + 0x7fffu + ((w.u >> 16) & 1u);
    return (u16)(r >> 16);
}

// ---------------- LayerNorm: one wave per row, float4 + shuffle reduce (proven r7) ----------------
__global__ __launch_bounds__(256) void ln_wave(const float* __restrict__ x, const float* __restrict__ g,
                                               const float* __restrict__ b, float* __restrict__ y) {
    int t = threadIdx.x, w = t >> 6, l = t & 63;
    int row = blockIdx.x * 4 + w;
    const float* xr = x + (size_t)row * DMODEL;
    float4 v = *reinterpret_cast<const float4*>(xr + l * 4);
    float s = v.x + v.y + v.z + v.w;
    for (int off = 1; off < 64; off <<= 1) s += __shfl_xor(s, off);
    float mean = s * (1.0f / 256.0f);
    float4 dv = make_float4(v.x - mean, v.y - mean, v.z - mean, v.w - mean);
    float vs = dv.x * dv.x + dv.y * dv.y + dv.z * dv.z + dv.w * dv.w;
    for (int off = 1; off < 64; off <<= 1) vs += __shfl_xor(vs, off);
    float rs = rsqrtf(vs * (1.0f / 256.0f) + 1e-5f);
    float4 gg = *reinterpret_cast<const float4*>(g + l * 4);
    float4 bb = *reinterpret_cast<const float4*>(b + l * 4);
    float4 out = make_float4(dv.x * rs * gg.x + bb.x, dv.y * rs * gg.y + bb.y,
                             dv.z * rs * gg.z + bb.z, dv.w * rs * gg.w + bb.w);
    *reinterpret_cast<float4*>(y + (size_t)row * DMODEL + l * 4) = out;
}

// ---------------- Weight convert v2: LDS tile transpose, coalesced both sides ----------------
// W[K][N] fp32 -> th[n][k], tl[n][k] bf16 (bit-identical to r12 wconv output).
__global__ __launch_bounds__(256) void wconv2(const float* __restrict__ W, u16* __restrict__ th,
                                              u16* __restrict__ tl, int K, int N) {
    __shared__ float T[64][65];
    int k0 = blockIdx.y * 64, n0 = blockIdx.x * 64;
    int t = threadIdx.x;
    int r = t >> 4, c4 = (t & 15) * 4;
#pragma unroll
    for (int i = 0; i < 4; i++) {
        float4 x = *reinterpret_cast<const float4*>(W + (size_t)(k0 + r + 16 * i) * N + n0 + c4);
        T[r + 16 * i][c4] = x.x; T[r + 16 * i][c4 + 1] = x.y;
        T[r + 16 * i][c4 + 2] = x.z; T[r + 16 * i][c4 + 3] = x.w;
    }
    __syncthreads();
#pragma unroll
    for (int i = 0; i < 4; i++) {
        int n = r + 16 * i;
        u16x4 h4, l4;
#pragma unroll
        for (int j = 0; j < 4; j++) {
            float v = T[c4 + j][n];
            u16 h = f2bf(v);
            h4[j] = h; l4[j] = f2bf(v - bf2f(h));
        }
        *reinterpret_cast<u16x4*>(th + (size_t)(n0 + n) * K + k0 + c4) = h4;
        *reinterpret_cast<u16x4*>(tl + (size_t)(n0 + n) * K + k0 + c4) = l4;
    }
}

// ---------------- MFMA GEMM (bf16x2) -- proven r12 ----------------
__global__ __launch_bounds__(256) void gemm_mx(const float* __restrict__ A, const u16* __restrict__ Bth,
                                               const u16* __restrict__ Btl, const float* __restrict__ bias,
                                               const float* __restrict__ resid, float* __restrict__ C,
                                               int M, int N, int K, int fuse_gelu) {
    __shared__ u16 Ah[128][56], Al[128][56];
    __shared__ u16 Bh[64][56],  Bl[64][56];
    int t = threadIdx.x;
    int m0 = blockIdx.y * 128, n0 = blockIdx.x * 64;
    int L = t & 63, w = t >> 6, fr = L & 15, quad = L >> 4;
    int sm = t >> 1, skh = (t & 1) * 16;
    int sn = t >> 2, skq = (t & 3) * 8;
    f32x4 acc[2][4];
#pragma unroll
    for (int i = 0; i < 2; i++)
#pragma unroll
        for (int j = 0; j < 4; j++) acc[i][j] = (f32x4){0.0f, 0.0f, 0.0f, 0.0f};

    for (int k0 = 0; k0 < K; k0 += 32) {
        __syncthreads();
        {
            const float* asrc = A + (size_t)(m0 + sm) * K + k0 + skh;
            float4 x0 = *reinterpret_cast<const float4*>(asrc);
            float4 x1 = *reinterpret_cast<const float4*>(asrc + 4);
            float4 x2 = *reinterpret_cast<const float4*>(asrc + 8);
            float4 x3 = *reinterpret_cast<const float4*>(asrc + 12);
            float xs[16] = {x0.x, x0.y, x0.z, x0.w, x1.x, x1.y, x1.z, x1.w,
                            x2.x, x2.y, x2.z, x2.w, x3.x, x3.y, x3.z, x3.w};
            u16x8 h0, h1, l0, l1;
#pragma unroll
            for (int j = 0; j < 8; j++) {
                u16 ha = f2bf(xs[j]);     h0[j] = ha; l0[j] = f2bf(xs[j] - bf2f(ha));
                u16 hb = f2bf(xs[j + 8]); h1[j] = hb; l1[j] = f2bf(xs[j + 8] - bf2f(hb));
            }
            *reinterpret_cast<u16x8*>(&Ah[sm][skh])     = h0;
            *reinterpret_cast<u16x8*>(&Ah[sm][skh + 8]) = h1;
            *reinterpret_cast<u16x8*>(&Al[sm][skh])     = l0;
            *reinterpret_cast<u16x8*>(&Al[sm][skh + 8]) = l1;
        }
        {
            size_t go = (size_t)(n0 + sn) * K + k0 + skq;
            *reinterpret_cast<u16x8*>(&Bh[sn][skq]) = *reinterpret_cast<const u16x8*>(Bth + go);
            *reinterpret_cast<u16x8*>(&Bl[sn][skq]) = *reinterpret_cast<const u16x8*>(Btl + go);
        }
        __syncthreads();
        s16x8 ah[2], al[2];
#pragma unroll
        for (int mi = 0; mi < 2; mi++) {
            int row = w * 32 + mi * 16 + fr;
            ah[mi] = *reinterpret_cast<s16x8*>(&Ah[row][quad * 8]);
            al[mi] = *reinterpret_cast<s16x8*>(&Al[row][quad * 8]);
        }
#pragma unroll
        for (int ni = 0; ni < 4; ni++) {
            int rn = ni * 16 + fr;
            s16x8 bhf = *reinterpret_cast<s16x8*>(&Bh[rn][quad * 8]);
            s16x8 blf = *reinterpret_cast<s16x8*>(&Bl[rn][quad * 8]);
#pragma unroll
            for (int mi = 0; mi < 2; mi++) {
                acc[mi][ni] = __builtin_amdgcn_mfma_f32_16x16x32_bf16(ah[mi], bhf, acc[mi][ni], 0, 0, 0);
                acc[mi][ni] = __builtin_amdgcn_mfma_f32_16x16x32_bf16(ah[mi], blf, acc[mi][ni], 0, 0, 0);
                acc[mi][ni] = __builtin_amdgcn_mfma_f32_16x16x32_bf16(al[mi], bhf, acc[mi][ni], 0, 0, 0);
            }
        }
    }
#pragma unroll
    for (int mi = 0; mi < 2; mi++) {
#pragma unroll
        for (int ni = 0; ni < 4; ni++) {
#pragma unroll
            for (int r = 0; r < 4; r++) {
                int row = m0 + w * 32 + mi * 16 + quad * 4 + r;
                int col = n0 + ni * 16 + fr;
                float v = acc[mi][ni][r];
                if (bias) v += bias[col];
                if (fuse_gelu) v = 0.5f * v * (1.0f + erff(v * 0.70710678118654752f));
                if (resid) v += resid[(size_t)row * N + col];
                C[(size_t)row * N + col] = v;
            }
        }
    }
}

// ---------------- Attention v6: MFMA flash (bf16x2 on Q,K,P,V -> error ~1e-5) ----------------
// Fragment layouts identical to the r12-proven gemm_mx (A rows / B^T rows / D col=lane&15,row=quad*4+r).
// P: D-layout -> wave-private LDS -> A-layout (same-wave LDS ordering, proven r9).
__global__ __launch_bounds__(256) void attn6(const float* __restrict__ q, const float* __restrict__ kv,
                                             float* __restrict__ o) {
    int bh = blockIdx.x, b = bh >> 3, h = bh & 7;
    int qt = blockIdx.y;
    int t = threadIdx.x, L = t & 63, w = t >> 6;
    int fr = L & 15, quad = L >> 4;
    __shared__ u16 QH[64][40], QL[64][40];   // stride 40: b128 16B-aligned, 2-way banks
    __shared__ u16 KH[64][40], KL[64][40];
    __shared__ u16 VTH[32][72], VTL[32][72]; // V^T[d][kc], stride 72
    __shared__ u16 PH[4][16][72], PL[4][16][72];  // per-wave P tile
    const float scale = 0.17677669529663687f;  // 1/sqrt(32)
    const float* kbase = kv + (size_t)b * 1024 * 512 + h * 32;
    const float* vbase = kbase + 256;

    {   // stage Q 64x32: thread -> row t>>2, dims (t&3)*8..+7
        int qr = t >> 2, d0 = (t & 3) * 8;
        const float* src = q + ((size_t)(b * 1024 + qt * 64 + qr)) * DMODEL + h * 32 + d0;
        float4 x0 = *reinterpret_cast<const float4*>(src);
        float4 x1 = *reinterpret_cast<const float4*>(src + 4);
        float xs[8] = {x0.x, x0.y, x0.z, x0.w, x1.x, x1.y, x1.z, x1.w};
        u16x8 hh, ll;
#pragma unroll
        for (int j = 0; j < 8; j++) { u16 hv = f2bf(xs[j]); hh[j] = hv; ll[j] = f2bf(xs[j] - bf2f(hv)); }
        *reinterpret_cast<u16x8*>(&QH[qr][d0]) = hh;
        *reinterpret_cast<u16x8*>(&QL[qr][d0]) = ll;
    }
    __syncthreads();
    s16x8 aqh = *reinterpret_cast<s16x8*>(&QH[w * 16 + fr][quad * 8]);  // wave-row A-frags, hoisted
    s16x8 aql = *reinterpret_cast<s16x8*>(&QL[w * 16 + fr][quad * 8]);

    float m_i[4], l_i[4];
    f32x4 acc_o[2];
#pragma unroll
    for (int r = 0; r < 4; r++) { m_i[r] = -1e30f; l_i[r] = 0.0f; }
    acc_o[0] = (f32x4){0.0f, 0.0f, 0.0f, 0.0f};
    acc_o[1] = (f32x4){0.0f, 0.0f, 0.0f, 0.0f};

    for (int kt = 0; kt < 16; kt++) {
        __syncthreads();   // protect K/VT from prior-iteration readers
        {   // stage K rows (split): row t>>2, dims (t&3)*8..+7
            int kr = t >> 2, d0 = (t & 3) * 8;
            const float* src = kbase + (size_t)(kt * 64 + kr) * 512 + d0;
            float4 x0 = *reinterpret_cast<const float4*>(src);
            float4 x1 = *reinterpret_cast<const float4*>(src + 4);
            float xs[8] = {x0.x, x0.y, x0.z, x0.w, x1.x, x1.y, x1.z, x1.w};
            u16x8 hh, ll;
#pragma unroll
            for (int j = 0; j < 8; j++) { u16 hv = f2bf(xs[j]); hh[j] = hv; ll[j] = f2bf(xs[j] - bf2f(hv)); }
            *reinterpret_cast<u16x8*>(&KH[kr][d0]) = hh;
            *reinterpret_cast<u16x8*>(&KL[kr][d0]) = ll;
        }
        {   // stage V transposed (split): thread -> kc pair 2p,2p+1, dims (t&7)*4..+3
            int vp = t >> 3, vd0 = (t & 7) * 4;
            const float* s0 = vbase + (size_t)(kt * 64 + 2 * vp) * 512 + vd0;
            float4 a0 = *reinterpret_cast<const float4*>(s0);
            float4 a1 = *reinterpret_cast<const float4*>(s0 + 512);
            float r0[4] = {a0.x, a0.y, a0.z, a0.w};
            float r1[4] = {a1.x, a1.y, a1.z, a1.w};
#pragma unroll
            for (int i = 0; i < 4; i++) {
                int d = vd0 + i;
                u16 h0 = f2bf(r0[i]), l0 = f2bf(r0[i] - bf2f(h0));
                u16 h1 = f2bf(r1[i]), l1 = f2bf(r1[i] - bf2f(h1));
                *reinterpret_cast<u32*>(&VTH[d][2 * vp]) = (u32)h0 | ((u32)h1 << 16);
                *reinterpret_cast<u32*>(&VTL[d][2 * vp]) = (u32)l0 | ((u32)l1 << 16);
            }
        }
        __syncthreads();
        // S = Q K^T : 4 n-subtiles, bf16x2 (3 MFMA each)
        f32x4 s[4];
#pragma unroll
        for (int ni = 0; ni < 4; ni++) {
            s16x8 bkh = *reinterpret_cast<s16x8*>(&KH[ni * 16 + fr][quad * 8]);
            s16x8 bkl = *reinterpret_cast<s16x8*>(&KL[ni * 16 + fr][quad * 8]);
            f32x4 c = (f32x4){0.0f, 0.0f, 0.0f, 0.0f};
            c = __builtin_amdgcn_mfma_f32_16x16x32_bf16(aqh, bkh, c, 0, 0, 0);
            c = __builtin_amdgcn_mfma_f32_16x16x32_bf16(aqh, bkl, c, 0, 0, 0);
            c = __builtin_amdgcn_mfma_f32_16x16x32_bf16(aql, bkh, c, 0, 0, 0);
            s[ni] = c;
        }
        // online softmax: lane owns rows quad*4+r, cols ni*16+fr; row spans 16 lanes (same quad)
        float alpha[4];
#pragma unroll
        for (int r = 0; r < 4; r++) {
            float s0 = s[0][r] * scale, s1 = s[1][r] * scale;
            float s2 = s[2][r] * scale, s3 = s[3][r] * scale;
            float ml = fmaxf(fmaxf(s0, s1), fmaxf(s2, s3));
            for (int off = 1; off < 16; off <<= 1) ml = fmaxf(ml, __shfl_xor(ml, off));
            float mnew = fmaxf(m_i[r], ml);
            alpha[r] = __expf(m_i[r] - mnew);
            m_i[r] = mnew;
            float p0 = __expf(s0 - mnew), p1 = __expf(s1 - mnew);
            float p2 = __expf(s2 - mnew), p3 = __expf(s3 - mnew);
            float rs = p0 + p1 + p2 + p3;
            for (int off = 1; off < 16; off <<= 1) rs += __shfl_xor(rs, off);
            l_i[r] = l_i[r] * alpha[r] + rs;
            int row = quad * 4 + r;
            float ps[4] = {p0, p1, p2, p3};
#pragma unroll
            for (int ni = 0; ni < 4; ni++) {
                u16 ph = f2bf(ps[ni]);
                PH[w][row][ni * 16 + fr] = ph;
                PL[w][row][ni * 16 + fr] = f2bf(ps[ni] - bf2f(ph));
            }
        }
        acc_o[0][0] *= alpha[0]; acc_o[0][1] *= alpha[1]; acc_o[0][2] *= alpha[2]; acc_o[0][3] *= alpha[3];
        acc_o[1][0] *= alpha[0]; acc_o[1][1] *= alpha[1]; acc_o[1][2] *= alpha[2]; acc_o[1][3] *= alpha[3];
        // PV: O += P V ; P wave-private (same-wave LDS write->read ordering)
#pragma unroll
        for (int ks = 0; ks < 2; ks++) {
            s16x8 aph = *reinterpret_cast<s16x8*>(&PH[w][fr][ks * 32 + quad * 8]);
            s16x8 apl = *reinterpret_cast<s16x8*>(&PL[w][fr][ks * 32 + quad * 8]);
#pragma unroll
            for (int ns = 0; ns < 2; ns++) {
                s16x8 bvh = *reinterpret_cast<s16x8*>(&VTH[ns * 16 + fr][ks * 32 + quad * 8]);
                s16x8 bvl = *reinterpret_cast<s16x8*>(&VTL[ns * 16 + fr][ks * 32 + quad * 8]);
                acc_o[ns] = __builtin_amdgcn_mfma_f32_16x16x32_bf16(aph, bvh, acc_o[ns], 0, 0, 0);
                acc_o[ns] = __builtin_amdgcn_mfma_f32_16x16x32_bf16(aph, bvl, acc_o[ns], 0, 0, 0);
                acc_o[ns] = __builtin_amdgcn_mfma_f32_16x16x32_bf16(apl, bvh, acc_o[ns], 0, 0, 0);
            }
        }
    }
    // write O: row = quad*4+r of wave tile, col = ns*16+fr
#pragma unroll
    for (int r = 0; r < 4; r++) {
        float invl = 1.0f / l_i[r];
        size_t rowbase = ((size_t)(b * 1024 + qt * 64 + w * 16 + quad * 4 + r)) * DMODEL + h * 32;
        o[rowbase + fr] = acc_o[0][r] * invl;
        o[rowbase + 16 + fr] = acc_o[1][r] * invl;
    }
}

// ---------------- K-means v2 (proven r10/r11) ----------------
__global__ __launch_bounds__(256) void km_zero0(float* __restrict__ sums, float* __restrict__ counts) {
    int i = blockIdx.x * 256 + threadIdx.x;
    if (i < NCLUST * DMODEL) sums[i] = 0.0f;
    if (i < NCLUST) counts[i] = 0.0f;
}

__global__ __launch_bounds__(64) void csq_k(const float* __restrict__ centers, float* __restrict__ csq) {
    int j = blockIdx.x, l = threadIdx.x;
    float4 c4 = *reinterpret_cast<const float4*>(centers + j * DMODEL + l * 4);
    float s = c4.x * c4.x + c4.y * c4.y + c4.z * c4.z + c4.w * c4.w;
    for (int off = 1; off < 64; off <<= 1) s += __shfl_xor(s, off);
    if (l == 0) csq[j] = s;
}

__global__ __launch_bounds__(256) void km_dist(const float* __restrict__ A, const float* __restrict__ Cn,
                                               float* __restrict__ dot) {
    __shared__ float As[16][68];
    __shared__ float Bs[16][64];
    int t = threadIdx.x, tx = t & 15, ty = t >> 4;
    int m0 = blockIdx.x * 64;
    int mr = t >> 2, kq = (t & 3) * 4;
    int jb = t & 63, kb = (t >> 6) * 4;
    float acc[4][4] = {};
    for (int k0 = 0; k0 < 256; k0 += 16) {
        __syncthreads();
        {
            float4 a4 = *reinterpret_cast<const float4*>(A + (size_t)(m0 + mr) * DMODEL + k0 + kq);
            As[kq][mr] = a4.x; As[kq + 1][mr] = a4.y; As[kq + 2][mr] = a4.z; As[kq + 3][mr] = a4.w;
        }
        {
            float4 c4 = *reinterpret_cast<const float4*>(Cn + (size_t)jb * DMODEL + k0 + kb);
            Bs[kb][jb] = c4.x; Bs[kb + 1][jb] = c4.y; Bs[kb + 2][jb] = c4.z; Bs[kb + 3][jb] = c4.w;
        }
        __syncthreads();
#pragma unroll
        for (int kk = 0; kk < 16; kk++) {
            float4 a4 = *reinterpret_cast<float4*>(&As[kk][ty * 4]);
            float4 b4 = *reinterpret_cast<float4*>(&Bs[kk][tx * 4]);
            float a[4] = {a4.x, a4.y, a4.z, a4.w};
            float bf[4] = {b4.x, b4.y, b4.z, b4.w};
#pragma unroll
            for (int i = 0; i < 4; i++)
#pragma unroll
                for (int j = 0; j < 4; j++) acc[i][j] += a[i] * bf[j];
        }
    }
#pragma unroll
    for (int i = 0; i < 4; i++)
#pragma unroll
        for (int j = 0; j < 4; j++)
            dot[(size_t)(m0 + ty * 4 + i) * NCLUST + tx * 4 + j] = acc[i][j];
}

__global__ __launch_bounds__(256) void km_argmin_segsum(const float* __restrict__ dot, const float* __restrict__ csq,
                                                        const float* __restrict__ xf, int* __restrict__ labels,
                                                        float* __restrict__ counts, float* __restrict__ sums,
                                                        int do_seg) {
    __shared__ float lsum[NCLUST][DMODEL];
    __shared__ int lab_s[128];
    int t = threadIdx.x, w = t >> 6, l = t & 63;
    int base = blockIdx.x * 128;
    float cs = csq[l];
    for (int p = 0; p < 32; p++) {
        int i = base + w * 32 + p;
        float val = cs - 2.0f * dot[(size_t)i * NCLUST + l];
        float best = val; int bi = l;
        for (int off = 1; off < 64; off <<= 1) {
            float ov = __shfl_xor(best, off);
            int oi = __shfl_xor(bi, off);
            if (ov < best || (ov == best && oi < bi)) { best = ov; bi = oi; }
        }
        if (l == 0) {
            labels[i] = bi;
            lab_s[w * 32 + p] = bi;
            if (do_seg) atomicAdd(&counts[bi], 1.0f);
        }
    }
    if (!do_seg) return;
    for (int j = 0; j < NCLUST; j++) lsum[j][t] = 0.0f;
    __syncthreads();
    for (int p = 0; p < 128; p++) {
        int lab = lab_s[p];
        lsum[lab][t] += xf[(size_t)(base + p) * DMODEL + t];
    }
    for (int j = 0; j < NCLUST; j++) atomicAdd(&sums[j * DMODEL + t], lsum[j][t]);
}

__global__ __launch_bounds__(256) void km_update_zero(float* __restrict__ centers, float* __restrict__ sums,
                                                      float* __restrict__ counts, float* __restrict__ csq) {
    __shared__ float red[256];
    int j = blockIdx.x, d = threadIdx.x;
    float c = counts[j];
    float cv = centers[j * DMODEL + d];
    if (c > 0.0f) cv = sums[j * DMODEL + d] / fmaxf(c, 1.0f);
    centers[j * DMODEL + d] = cv;
    red[d] = cv * cv;
    __syncthreads();
    for (int off = 128; off; off >>= 1) { if (d < off) red[d] += red[d + off]; __syncthreads(); }
    if (d == 0) { csq[j] = red[0]; counts[j] = 0.0f; }
    sums[j * DMODEL + d] = 0.0f;
}

__global__ __launch_bounds__(256) void nproj(const float* __restrict__ centers, const float* __restrict__ kW,
                                             const float* __restrict__ kb2, float* __restrict__ outc) {
    int idx = blockIdx.x * 256 + threadIdx.x;
    if (idx >= NCLUST * DMODEL) return;
    int row = idx >> 8, col = idx & 255;
    const float* cr = centers + row * DMODEL;
    float acc = 0.0f;
    for (int d = 0; d < DMODEL; d++) acc += cr[d] * kW[(size_t)d * DMODEL + col];
    outc[idx] = acc + kb2[col];
}

__global__ __launch_bounds__(256) void km_gather(const int* __restrict__ labels, const float* __restrict__ outc,
                                                 float* __restrict__ out) {
    int i = blockIdx.x, t = threadIdx.x;
    int lab = labels[i];
    out[(size_t)i * DMODEL + t] = outc[lab * DMODEL + t];
}

extern "C" void kernel_launch(void* const* d_in, const int* in_sizes, int n_in,
                              void* d_out, int out_size, void* d_ws, size_t ws_size,
                              hipStream_t stream) {
    const float* x_in  = (const float*)d_in[0];
    const float* ln1_g = (const float*)d_in[1];
    const float* ln1_b = (const float*)d_in[2];
    const float* Wq    = (const float*)d_in[3];
    const float* Wkv   = (const float*)d_in[4];
    const float* Wo    = (const float*)d_in[5];
    const float* bo    = (const float*)d_in[6];
    const float* ln2_g = (const float*)d_in[7];
    const float* ln2_b = (const float*)d_in[8];
    const float* W1    = (const float*)d_in[9];
    const float* b1    = (const float*)d_in[10];
    const float* W2    = (const float*)d_in[11];
    const float* b2    = (const float*)d_in[12];
    const float* kWp   = (const float*)d_in[13];
    const float* kbp   = (const float*)d_in[14];
    float* out = (float*)d_out;

    const size_t NEEDED = 53477376;
    if (ws_size < NEEDED) {
        hipMemsetAsync(d_out, 0, (size_t)out_size * sizeof(float), stream);
        return;   // signature: absmax ~0.707 => workspace too small
    }

    char* ws = (char*)d_ws;
    float* xf      = (float*)(ws);
    float* xn      = (float*)(ws + 8388608);
    float* ao      = xn;
    float* qb      = (float*)(ws + 16777216);
    float* kvb     = (float*)(ws + 25165824);
    float* hb      = (float*)(ws + 16777216);   // 32 MB span during FFN (qb/kvb dead)
    float* dotb    = qb;
    float* centers = (float*)(ws + 41943040);
    float* sums    = (float*)(ws + 42008576);
    float* counts  = (float*)(ws + 42074112);
    float* csqb    = (float*)(ws + 42074368);
    int*   labels  = (int*)  (ws + 42075136);
    float* outc    = (float*)(ws + 42107904);
    u16*   wr      = (u16*)  (ws + 50331648);
    u16 *wqh = wr,            *wql = wr + 65536;
    u16 *wkvh = wr + 131072,  *wkvl = wr + 262144;
    u16 *woh = wr + 393216,   *wol = wr + 458752;
    u16 *w1h = wr + 524288,   *w1l = wr + 786432;
    u16 *w2h = wr + 1048576,  *w2l = wr + 1310720;

    hipMemcpyAsync(xf, x_in, (size_t)BN * DMODEL * sizeof(float), hipMemcpyDeviceToDevice, stream);

    for (int l = 0; l < 4; l++) {
        wconv2<<<dim3(4, 4), 256, 0, stream>>>(Wq + (size_t)l * 65536, wqh, wql, 256, 256);
        wconv2<<<dim3(8, 4), 256, 0, stream>>>(Wkv + (size_t)l * 131072, wkvh, wkvl, 256, 512);
        wconv2<<<dim3(4, 4), 256, 0, stream>>>(Wo + (size_t)l * 65536, woh, wol, 256, 256);
        wconv2<<<dim3(16, 4), 256, 0, stream>>>(W1 + (size_t)l * 262144, w1h, w1l, 256, 1024);
        wconv2<<<dim3(4, 16), 256, 0, stream>>>(W2 + (size_t)l * 262144, w2h, w2l, 1024, 256);

        ln_wave<<<BN / 4, 256, 0, stream>>>(xf, ln1_g + l * 256, ln1_b + l * 256, xn);
        gemm_mx<<<dim3(4, 64), 256, 0, stream>>>(xn, wqh, wql, nullptr, nullptr, qb, BN, 256, 256, 0);
        gemm_mx<<<dim3(8, 64), 256, 0, stream>>>(xn, wkvh, wkvl, nullptr, nullptr, kvb, BN, 512, 256, 0);
        attn6<<<dim3(64, 16), 256, 0, stream>>>(qb, kvb, ao);
        gemm_mx<<<dim3(4, 64), 256, 0, stream>>>(ao, woh, wol, bo + l * 256, xf, xf, BN, 256, 256, 0);
        ln_wave<<<BN / 4, 256, 0, stream>>>(xf, ln2_g + l * 256, ln2_b + l * 256, xn);
        gemm_mx<<<dim3(16, 64), 256, 0, stream>>>(xn, w1h, w1l, b1 + l * 1024, nullptr, hb, BN, 1024, 256, 1);
        gemm_mx<<<dim3(4, 64), 256, 0, stream>>>(hb, w2h, w2l, b2 + l * 256, xf, xf, BN, 256, 1024, 0);
    }

    hipMemcpyAsync(centers, xf, NCLUST * DMODEL * sizeof(float), hipMemcpyDeviceToDevice, stream);
    km_zero0<<<64, 256, 0, stream>>>(sums, counts);
    csq_k<<<64, 64, 0, stream>>>(centers, csqb);
    for (int it = 0; it < 10; it++) {
        km_dist<<<128, 256, 0, stream>>>(xf, centers, dotb);
        km_argmin_segsum<<<64, 256, 0, stream>>>(dotb, csqb, xf, labels, counts, sums, 1);
        km_update_zero<<<64, 256, 0, stream>>>(centers, sums, counts, csqb);
    }
    km_dist<<<128, 256, 0, stream>>>(xf, centers, dotb);
    km_argmin_segsum<<<64, 256, 0, stream>>>(dotb, csqb, xf, labels, counts, sums, 0);
    nproj<<<64, 256, 0, stream>>>(centers, kWp, kbp, outc);
    km_gather<<<BN, 256, 0, stream>>>(labels, outc, out);
}